// Round 1
// baseline (354.572 us; speedup 1.0000x reference)
//
#include <hip/hip_runtime.h>
#include <hip/hip_bf16.h>

#define N_NODES 50000
#define N_EDGES 600000
#define NF 128
#define NC 10

// ---------------- degree / dinv ----------------
__global__ void k_count(const int* __restrict__ src, const int* __restrict__ dst,
                        const float* __restrict__ ew, float* __restrict__ deg,
                        int* __restrict__ cnt) {
    int e = blockIdx.x * blockDim.x + threadIdx.x;
    if (e >= N_EDGES) return;
    int d = dst[e];
    atomicAdd(&deg[d], ew[e]);
    atomicAdd(&cnt[d], 1);
}

__global__ void k_dinv(const float* __restrict__ deg, float* __restrict__ dinv) {
    int i = blockIdx.x * blockDim.x + threadIdx.x;
    if (i >= N_NODES) return;
    dinv[i] = rsqrtf(deg[i] + 1.0f);
}

// ---------------- exclusive scan (3 kernels) ----------------
__global__ void k_scan1(const int* __restrict__ cnt, int* __restrict__ rowptr,
                        int* __restrict__ bsum, int n) {
    __shared__ int sh[256];
    int t = threadIdx.x;
    int i = blockIdx.x * 256 + t;
    int v = (i < n) ? cnt[i] : 0;
    sh[t] = v;
    __syncthreads();
    for (int off = 1; off < 256; off <<= 1) {
        int x = 0;
        if (t >= off) x = sh[t - off];
        __syncthreads();
        sh[t] += x;
        __syncthreads();
    }
    if (i < n) rowptr[i] = sh[t] - v;          // block-local exclusive
    if (t == 255) bsum[blockIdx.x] = sh[255];  // block total
}

__global__ void k_scan2(int* __restrict__ bsum, int nb) {
    __shared__ int sh[256];
    int t = threadIdx.x;
    int v = (t < nb) ? bsum[t] : 0;
    sh[t] = v;
    __syncthreads();
    for (int off = 1; off < 256; off <<= 1) {
        int x = 0;
        if (t >= off) x = sh[t - off];
        __syncthreads();
        sh[t] += x;
        __syncthreads();
    }
    if (t < nb) bsum[t] = sh[t] - v;           // exclusive block offsets
}

__global__ void k_scan3(int* __restrict__ rowptr, const int* __restrict__ bsum,
                        int* __restrict__ cursor, int n) {
    int t = threadIdx.x;
    int i = blockIdx.x * 256 + t;
    if (i < n) {
        int r = rowptr[i] + bsum[blockIdx.x];
        rowptr[i] = r;
        cursor[i] = r;
    }
    if (blockIdx.x == 0 && t == 0) rowptr[n] = N_EDGES;
}

// ---------------- CSR scatter (counting sort by dst) ----------------
__global__ void k_scatter(const int* __restrict__ src, const int* __restrict__ dst,
                          const float* __restrict__ ew, const float* __restrict__ dinv,
                          int* __restrict__ cursor, int* __restrict__ esrc,
                          float* __restrict__ enorm) {
    int e = blockIdx.x * blockDim.x + threadIdx.x;
    if (e >= N_EDGES) return;
    int s = src[e], d = dst[e];
    int pos = atomicAdd(&cursor[d], 1);
    esrc[pos]  = s;
    enorm[pos] = dinv[s] * ew[e] * dinv[d];
}

// ---------------- GEMM: Y[M,128] = X[M,128] @ W[128,128] ----------------
__global__ __launch_bounds__(256) void k_gemm128(const float* __restrict__ X,
                                                 const float* __restrict__ W,
                                                 float* __restrict__ Y, int M) {
    __shared__ float Wl[128][128];  // 64 KiB
    __shared__ float Xl[16][128];   // 8 KiB
    int t = threadIdx.x;
    for (int i = t; i < 128 * 128 / 4; i += 256)
        ((float4*)Wl)[i] = ((const float4*)W)[i];
    __syncthreads();

    int cg = t & 31;   // col group: cols cg*4 .. cg*4+3
    int rp = t >> 5;   // 0..7  -> local rows 2*rp, 2*rp+1
    for (int g = blockIdx.x; g * 16 < M; g += gridDim.x) {
        int row0 = g * 16;
        for (int i = t; i < 512; i += 256) {   // 16 rows * 32 float4
            int lr = i >> 5, k4 = i & 31;
            int r = row0 + lr;
            float4 v = make_float4(0.f, 0.f, 0.f, 0.f);
            if (r < M) v = ((const float4*)(X + (size_t)r * 128))[k4];
            ((float4*)&Xl[lr][0])[k4] = v;
        }
        __syncthreads();
        float4 a0 = make_float4(0.f, 0.f, 0.f, 0.f);
        float4 a1 = make_float4(0.f, 0.f, 0.f, 0.f);
        int r0 = rp * 2, r1 = rp * 2 + 1;
        for (int k = 0; k < 128; ++k) {
            float4 wv = ((float4*)&Wl[k][0])[cg];
            float x0 = Xl[r0][k];
            float x1 = Xl[r1][k];
            a0.x += x0 * wv.x; a0.y += x0 * wv.y; a0.z += x0 * wv.z; a0.w += x0 * wv.w;
            a1.x += x1 * wv.x; a1.y += x1 * wv.y; a1.z += x1 * wv.z; a1.w += x1 * wv.w;
        }
        int gr0 = row0 + r0, gr1 = row0 + r1;
        if (gr0 < M) ((float4*)(Y + (size_t)gr0 * 128))[cg] = a0;
        if (gr1 < M) ((float4*)(Y + (size_t)gr1 * 128))[cg] = a1;
        __syncthreads();
    }
}

// ---------------- aggregation: one wave per node ----------------
template <int RELU>
__global__ __launch_bounds__(256) void k_agg(const float* __restrict__ h,
                                             const int* __restrict__ rowptr,
                                             const int* __restrict__ esrc,
                                             const float* __restrict__ enorm,
                                             const float* __restrict__ dinv,
                                             const float* __restrict__ bias,
                                             float* __restrict__ out) {
    int wid  = (blockIdx.x * blockDim.x + threadIdx.x) >> 6;  // node
    int lane = threadIdx.x & 63;
    if (wid >= N_NODES) return;
    float di  = dinv[wid];
    float di2 = di * di;
    float2 acc = ((const float2*)(h + (size_t)wid * 128))[lane];
    acc.x *= di2; acc.y *= di2;                       // self-loop term
    int p1 = rowptr[wid + 1];
    for (int p = rowptr[wid]; p < p1; ++p) {
        int   s = esrc[p];
        float w = enorm[p];
        float2 hv = ((const float2*)(h + (size_t)s * 128))[lane];
        acc.x += w * hv.x;
        acc.y += w * hv.y;
    }
    float2 bv = ((const float2*)bias)[lane];
    acc.x += bv.x; acc.y += bv.y;
    if (RELU) { acc.x = fmaxf(acc.x, 0.f); acc.y = fmaxf(acc.y, 0.f); }
    ((float2*)(out + (size_t)wid * 128))[lane] = acc;
}

// ---------------- final: out[N,10] = H[N,128] @ Wc[128,10] + bc ----------------
__global__ __launch_bounds__(256) void k_final(const float* __restrict__ H,
                                               const float* __restrict__ Wc,
                                               const float* __restrict__ bc,
                                               float* __restrict__ out) {
    int wid  = (blockIdx.x * blockDim.x + threadIdx.x) >> 6;
    int lane = threadIdx.x & 63;
    if (wid >= N_NODES) return;
    float2 hv = ((const float2*)(H + (size_t)wid * 128))[lane];
    int k0 = 2 * lane;
    float acc[NC];
#pragma unroll
    for (int c = 0; c < NC; ++c)
        acc[c] = hv.x * Wc[k0 * NC + c] + hv.y * Wc[(k0 + 1) * NC + c];
#pragma unroll
    for (int off = 32; off; off >>= 1)
#pragma unroll
        for (int c = 0; c < NC; ++c)
            acc[c] += __shfl_xor(acc[c], off, 64);
    if (lane < NC) out[(size_t)wid * NC + lane] = acc[lane] + bc[lane];
}

extern "C" void kernel_launch(void* const* d_in, const int* in_sizes, int n_in,
                              void* d_out, int out_size, void* d_ws, size_t ws_size,
                              hipStream_t stream) {
    const float* x   = (const float*)d_in[0];
    const int*   ei  = (const int*)d_in[1];
    const float* ew  = (const float*)d_in[2];
    const float* W1  = (const float*)d_in[3];
    const float* b1  = (const float*)d_in[4];
    const float* W2  = (const float*)d_in[5];
    const float* b2  = (const float*)d_in[6];
    const float* Wc  = (const float*)d_in[7];
    const float* bc  = (const float*)d_in[8];
    float*       out = (float*)d_out;

    const int* src = ei;
    const int* dst = ei + N_EDGES;

    // workspace carve-out (256B aligned)
    size_t off = 0;
    auto carve = [&](size_t bytes) {
        void* p = (char*)d_ws + off;
        off += (bytes + 255) & ~(size_t)255;
        return p;
    };
    float* h      = (float*)carve((size_t)N_NODES * 128 * 4);
    float* agg    = (float*)carve((size_t)N_NODES * 128 * 4);
    float* deg    = (float*)carve((size_t)N_NODES * 4);
    float* dinv   = (float*)carve((size_t)N_NODES * 4);
    int*   cnt    = (int*)carve((size_t)N_NODES * 4);
    int*   rowptr = (int*)carve((size_t)(N_NODES + 1) * 4);
    int*   cursor = (int*)carve((size_t)N_NODES * 4);
    int*   bsum   = (int*)carve(256 * 4);
    int*   esrc   = (int*)carve((size_t)N_EDGES * 4);
    float* enorm  = (float*)carve((size_t)N_EDGES * 4);
    (void)ws_size; (void)n_in; (void)in_sizes; (void)out_size;

    hipMemsetAsync(deg, 0, (size_t)N_NODES * 4, stream);
    hipMemsetAsync(cnt, 0, (size_t)N_NODES * 4, stream);

    int eb = (N_EDGES + 255) / 256;
    int nb = (N_NODES + 255) / 256;

    k_count<<<eb, 256, 0, stream>>>(src, dst, ew, deg, cnt);
    k_dinv<<<nb, 256, 0, stream>>>(deg, dinv);
    k_scan1<<<nb, 256, 0, stream>>>(cnt, rowptr, bsum, N_NODES);
    k_scan2<<<1, 256, 0, stream>>>(bsum, nb);
    k_scan3<<<nb, 256, 0, stream>>>(rowptr, bsum, cursor, N_NODES);
    k_scatter<<<eb, 256, 0, stream>>>(src, dst, ew, dinv, cursor, esrc, enorm);

    // layer 1
    k_gemm128<<<512, 256, 0, stream>>>(x, W1, h, N_NODES);
    k_agg<1><<<(N_NODES + 3) / 4, 256, 0, stream>>>(h, rowptr, esrc, enorm, dinv, b1, agg);
    // layer 2
    k_gemm128<<<512, 256, 0, stream>>>(agg, W2, h, N_NODES);
    k_agg<1><<<(N_NODES + 3) / 4, 256, 0, stream>>>(h, rowptr, esrc, enorm, dinv, b2, agg);
    // classifier
    k_final<<<(N_NODES + 3) / 4, 256, 0, stream>>>(agg, Wc, bc, out);
}

// Round 2
// 309.073 us; speedup vs baseline: 1.1472x; 1.1472x over previous
//
#include <hip/hip_runtime.h>
#include <hip/hip_bf16.h>

#define N_NODES 50000
#define N_EDGES 600000
#define NF 128
#define NC 10

// ---------------- degree count ----------------
__global__ void k_count(const int* __restrict__ src, const int* __restrict__ dst,
                        const float* __restrict__ ew, float* __restrict__ deg,
                        int* __restrict__ cnt) {
    int e = blockIdx.x * blockDim.x + threadIdx.x;
    if (e >= N_EDGES) return;
    int d = dst[e];
    atomicAdd(&deg[d], ew[e]);
    atomicAdd(&cnt[d], 1);
}

// ---------------- exclusive scan (3 kernels); scan1 also computes dinv ----------------
__global__ void k_scan1(const int* __restrict__ cnt, int* __restrict__ rowptr,
                        int* __restrict__ bsum, const float* __restrict__ deg,
                        float* __restrict__ dinv, int n) {
    __shared__ int sh[256];
    int t = threadIdx.x;
    int i = blockIdx.x * 256 + t;
    if (i < n) dinv[i] = rsqrtf(deg[i] + 1.0f);
    int v = (i < n) ? cnt[i] : 0;
    sh[t] = v;
    __syncthreads();
    for (int off = 1; off < 256; off <<= 1) {
        int x = 0;
        if (t >= off) x = sh[t - off];
        __syncthreads();
        sh[t] += x;
        __syncthreads();
    }
    if (i < n) rowptr[i] = sh[t] - v;          // block-local exclusive
    if (t == 255) bsum[blockIdx.x] = sh[255];  // block total
}

__global__ void k_scan2(int* __restrict__ bsum, int nb) {
    __shared__ int sh[256];
    int t = threadIdx.x;
    int v = (t < nb) ? bsum[t] : 0;
    sh[t] = v;
    __syncthreads();
    for (int off = 1; off < 256; off <<= 1) {
        int x = 0;
        if (t >= off) x = sh[t - off];
        __syncthreads();
        sh[t] += x;
        __syncthreads();
    }
    if (t < nb) bsum[t] = sh[t] - v;           // exclusive block offsets
}

__global__ void k_scan3(int* __restrict__ rowptr, const int* __restrict__ bsum,
                        int* __restrict__ cursor, int n) {
    int t = threadIdx.x;
    int i = blockIdx.x * 256 + t;
    if (i < n) {
        int r = rowptr[i] + bsum[blockIdx.x];
        rowptr[i] = r;
        cursor[i] = r;
    }
    if (blockIdx.x == 0 && t == 0) rowptr[n] = N_EDGES;
}

// ---------------- CSR scatter (counting sort by dst) ----------------
__global__ void k_scatter(const int* __restrict__ src, const int* __restrict__ dst,
                          const float* __restrict__ ew, const float* __restrict__ dinv,
                          int* __restrict__ cursor, int* __restrict__ esrc,
                          float* __restrict__ enorm) {
    int e = blockIdx.x * blockDim.x + threadIdx.x;
    if (e >= N_EDGES) return;
    int s = src[e], d = dst[e];
    int pos = atomicAdd(&cursor[d], 1);
    esrc[pos]  = s;
    enorm[pos] = dinv[s] * ew[e] * dinv[d];
}

// ---------------- GEMM: Y[M,128] = X[M,128] @ W[128,128] ----------------
// 256 thr: thread computes 4 rows x 4 cols. All LDS reads are b128.
__global__ __launch_bounds__(256) void k_gemm128(const float* __restrict__ X,
                                                 const float* __restrict__ W,
                                                 float* __restrict__ Y, int M) {
    __shared__ float Wl[128][128];  // 64 KiB
    __shared__ float Xl[32][128];   // 16 KiB
    int t = threadIdx.x;
    for (int i = t; i < 4096; i += 256)
        ((float4*)Wl)[i] = ((const float4*)W)[i];

    int tc = t & 31;   // col group: cols tc*4 .. tc*4+3
    int tr = t >> 5;   // row group: rows tr*4 .. tr*4+3
    for (int g = blockIdx.x; g * 32 < M; g += gridDim.x) {
        int row0 = g * 32;
        __syncthreads();   // Wl ready (first iter) / previous compute done
        for (int i = t; i < 1024; i += 256) {   // 32 rows * 32 float4
            int lr = i >> 5, k4 = i & 31;
            int r = row0 + lr;
            float4 v = make_float4(0.f, 0.f, 0.f, 0.f);
            if (r < M) v = ((const float4*)(X + (size_t)r * 128))[k4];
            ((float4*)&Xl[lr][0])[k4] = v;
        }
        __syncthreads();
        float4 a0 = make_float4(0.f,0.f,0.f,0.f);
        float4 a1 = a0, a2 = a0, a3 = a0;
        int r0 = tr * 4;
#pragma unroll 8
        for (int kc = 0; kc < 32; ++kc) {
            float4 x0 = ((float4*)&Xl[r0 + 0][0])[kc];
            float4 x1 = ((float4*)&Xl[r0 + 1][0])[kc];
            float4 x2 = ((float4*)&Xl[r0 + 2][0])[kc];
            float4 x3 = ((float4*)&Xl[r0 + 3][0])[kc];
            float4 w0 = ((float4*)&Wl[kc * 4 + 0][0])[tc];
            float4 w1 = ((float4*)&Wl[kc * 4 + 1][0])[tc];
            float4 w2 = ((float4*)&Wl[kc * 4 + 2][0])[tc];
            float4 w3 = ((float4*)&Wl[kc * 4 + 3][0])[tc];
#define FMA4(A, XV)                                                        \
            A.x += XV.x*w0.x + XV.y*w1.x + XV.z*w2.x + XV.w*w3.x;          \
            A.y += XV.x*w0.y + XV.y*w1.y + XV.z*w2.y + XV.w*w3.y;          \
            A.z += XV.x*w0.z + XV.y*w1.z + XV.z*w2.z + XV.w*w3.z;          \
            A.w += XV.x*w0.w + XV.y*w1.w + XV.z*w2.w + XV.w*w3.w;
            FMA4(a0, x0) FMA4(a1, x1) FMA4(a2, x2) FMA4(a3, x3)
#undef FMA4
        }
        int gr = row0 + r0;
        if (gr + 3 < M) {
            ((float4*)(Y + (size_t)(gr+0) * 128))[tc] = a0;
            ((float4*)(Y + (size_t)(gr+1) * 128))[tc] = a1;
            ((float4*)(Y + (size_t)(gr+2) * 128))[tc] = a2;
            ((float4*)(Y + (size_t)(gr+3) * 128))[tc] = a3;
        } else {
            if (gr+0 < M) ((float4*)(Y + (size_t)(gr+0) * 128))[tc] = a0;
            if (gr+1 < M) ((float4*)(Y + (size_t)(gr+1) * 128))[tc] = a1;
            if (gr+2 < M) ((float4*)(Y + (size_t)(gr+2) * 128))[tc] = a2;
            if (gr+3 < M) ((float4*)(Y + (size_t)(gr+3) * 128))[tc] = a3;
        }
    }
}

// ---------------- aggregation: one wave per node, 4-deep gather pipeline ----------------
template <int RELU>
__global__ __launch_bounds__(256) void k_agg(const float* __restrict__ h,
                                             const int* __restrict__ rowptr,
                                             const int* __restrict__ esrc,
                                             const float* __restrict__ enorm,
                                             const float* __restrict__ dinv,
                                             const float* __restrict__ bias,
                                             float* __restrict__ out) {
    int wid  = (blockIdx.x * blockDim.x + threadIdx.x) >> 6;  // node
    int lane = threadIdx.x & 63;
    if (wid >= N_NODES) return;
    float di  = dinv[wid];
    float di2 = di * di;
    float2 acc = ((const float2*)(h + (size_t)wid * 128))[lane];
    acc.x *= di2; acc.y *= di2;                       // self-loop term
    int p  = rowptr[wid];
    int p1 = rowptr[wid + 1];
    // 4-wide software pipeline: 4 outstanding 512B gathers per wave
    for (; p + 4 <= p1; p += 4) {
        int   s0 = esrc[p],     s1 = esrc[p + 1],  s2 = esrc[p + 2],  s3 = esrc[p + 3];
        float w0 = enorm[p],    w1 = enorm[p + 1], w2 = enorm[p + 2], w3 = enorm[p + 3];
        float2 v0 = ((const float2*)(h + (size_t)s0 * 128))[lane];
        float2 v1 = ((const float2*)(h + (size_t)s1 * 128))[lane];
        float2 v2 = ((const float2*)(h + (size_t)s2 * 128))[lane];
        float2 v3 = ((const float2*)(h + (size_t)s3 * 128))[lane];
        acc.x += w0 * v0.x + w1 * v1.x + w2 * v2.x + w3 * v3.x;
        acc.y += w0 * v0.y + w1 * v1.y + w2 * v2.y + w3 * v3.y;
    }
    for (; p < p1; ++p) {
        int   s = esrc[p];
        float w = enorm[p];
        float2 hv = ((const float2*)(h + (size_t)s * 128))[lane];
        acc.x += w * hv.x;
        acc.y += w * hv.y;
    }
    float2 bv = ((const float2*)bias)[lane];
    acc.x += bv.x; acc.y += bv.y;
    if (RELU) { acc.x = fmaxf(acc.x, 0.f); acc.y = fmaxf(acc.y, 0.f); }
    ((float2*)(out + (size_t)wid * 128))[lane] = acc;
}

// ---------------- final: out[N,10] = H[N,128] @ Wc[128,10] + bc ----------------
__global__ __launch_bounds__(256) void k_final(const float* __restrict__ H,
                                               const float* __restrict__ Wc,
                                               const float* __restrict__ bc,
                                               float* __restrict__ out) {
    int wid  = (blockIdx.x * blockDim.x + threadIdx.x) >> 6;
    int lane = threadIdx.x & 63;
    if (wid >= N_NODES) return;
    float2 hv = ((const float2*)(H + (size_t)wid * 128))[lane];
    int k0 = 2 * lane;
    float acc[NC];
#pragma unroll
    for (int c = 0; c < NC; ++c)
        acc[c] = hv.x * Wc[k0 * NC + c] + hv.y * Wc[(k0 + 1) * NC + c];
#pragma unroll
    for (int off = 32; off; off >>= 1)
#pragma unroll
        for (int c = 0; c < NC; ++c)
            acc[c] += __shfl_xor(acc[c], off, 64);
    if (lane < NC) out[(size_t)wid * NC + lane] = acc[lane] + bc[lane];
}

extern "C" void kernel_launch(void* const* d_in, const int* in_sizes, int n_in,
                              void* d_out, int out_size, void* d_ws, size_t ws_size,
                              hipStream_t stream) {
    const float* x   = (const float*)d_in[0];
    const int*   ei  = (const int*)d_in[1];
    const float* ew  = (const float*)d_in[2];
    const float* W1  = (const float*)d_in[3];
    const float* b1  = (const float*)d_in[4];
    const float* W2  = (const float*)d_in[5];
    const float* b2  = (const float*)d_in[6];
    const float* Wc  = (const float*)d_in[7];
    const float* bc  = (const float*)d_in[8];
    float*       out = (float*)d_out;

    const int* src = ei;
    const int* dst = ei + N_EDGES;

    size_t off = 0;
    auto carve = [&](size_t bytes) {
        void* p = (char*)d_ws + off;
        off += (bytes + 255) & ~(size_t)255;
        return p;
    };
    float* h      = (float*)carve((size_t)N_NODES * 128 * 4);
    float* agg    = (float*)carve((size_t)N_NODES * 128 * 4);
    float* deg    = (float*)carve((size_t)N_NODES * 4);
    float* dinv   = (float*)carve((size_t)N_NODES * 4);
    int*   cnt    = (int*)carve((size_t)N_NODES * 4);
    int*   rowptr = (int*)carve((size_t)(N_NODES + 1) * 4);
    int*   cursor = (int*)carve((size_t)N_NODES * 4);
    int*   bsum   = (int*)carve(256 * 4);
    int*   esrc   = (int*)carve((size_t)N_EDGES * 4);
    float* enorm  = (float*)carve((size_t)N_EDGES * 4);
    (void)ws_size; (void)n_in; (void)in_sizes; (void)out_size;

    hipMemsetAsync(deg, 0, (size_t)N_NODES * 4, stream);
    hipMemsetAsync(cnt, 0, (size_t)N_NODES * 4, stream);

    int eb = (N_EDGES + 255) / 256;
    int nb = (N_NODES + 255) / 256;

    k_count<<<eb, 256, 0, stream>>>(src, dst, ew, deg, cnt);
    k_scan1<<<nb, 256, 0, stream>>>(cnt, rowptr, bsum, deg, dinv, N_NODES);
    k_scan2<<<1, 256, 0, stream>>>(bsum, nb);
    k_scan3<<<nb, 256, 0, stream>>>(rowptr, bsum, cursor, N_NODES);
    k_scatter<<<eb, 256, 0, stream>>>(src, dst, ew, dinv, cursor, esrc, enorm);

    // layer 1
    k_gemm128<<<512, 256, 0, stream>>>(x, W1, h, N_NODES);
    k_agg<1><<<(N_NODES + 3) / 4, 256, 0, stream>>>(h, rowptr, esrc, enorm, dinv, b1, agg);
    // layer 2
    k_gemm128<<<512, 256, 0, stream>>>(agg, W2, h, N_NODES);
    k_agg<1><<<(N_NODES + 3) / 4, 256, 0, stream>>>(h, rowptr, esrc, enorm, dinv, b2, agg);
    // classifier
    k_final<<<(N_NODES + 3) / 4, 256, 0, stream>>>(agg, Wc, bc, out);
}

// Round 3
// 290.107 us; speedup vs baseline: 1.2222x; 1.0654x over previous
//
#include <hip/hip_runtime.h>
#include <hip/hip_bf16.h>

#define N_NODES 50000
#define N_EDGES 600000
#define NF 128
#define NC 10

// ---------------- count incoming edges (1 int atomic per edge) ----------------
__global__ void k_count(const int* __restrict__ dst, int* __restrict__ cnt) {
    int e = blockIdx.x * blockDim.x + threadIdx.x;
    if (e >= N_EDGES) return;
    atomicAdd(&cnt[dst[e]], 1);
}

// ---------------- exclusive scan (3 kernels) ----------------
__global__ void k_scan1(const int* __restrict__ cnt, int* __restrict__ rowptr,
                        int* __restrict__ bsum, int n) {
    __shared__ int sh[256];
    int t = threadIdx.x;
    int i = blockIdx.x * 256 + t;
    int v = (i < n) ? cnt[i] : 0;
    sh[t] = v;
    __syncthreads();
    for (int off = 1; off < 256; off <<= 1) {
        int x = 0;
        if (t >= off) x = sh[t - off];
        __syncthreads();
        sh[t] += x;
        __syncthreads();
    }
    if (i < n) rowptr[i] = sh[t] - v;          // block-local exclusive
    if (t == 255) bsum[blockIdx.x] = sh[255];  // block total
}

__global__ void k_scan2(int* __restrict__ bsum, int nb) {
    __shared__ int sh[256];
    int t = threadIdx.x;
    int v = (t < nb) ? bsum[t] : 0;
    sh[t] = v;
    __syncthreads();
    for (int off = 1; off < 256; off <<= 1) {
        int x = 0;
        if (t >= off) x = sh[t - off];
        __syncthreads();
        sh[t] += x;
        __syncthreads();
    }
    if (t < nb) bsum[t] = sh[t] - v;           // exclusive block offsets
}

__global__ void k_scan3(int* __restrict__ rowptr, const int* __restrict__ bsum,
                        int* __restrict__ cursor, int n) {
    int t = threadIdx.x;
    int i = blockIdx.x * 256 + t;
    if (i < n) {
        int r = rowptr[i] + bsum[blockIdx.x];
        rowptr[i] = r;
        cursor[i] = r;
    }
    if (blockIdx.x == 0 && t == 0) rowptr[n] = N_EDGES;
}

// ---------------- CSR scatter (counting sort by dst) ----------------
__global__ void k_scatter(const int* __restrict__ src, const int* __restrict__ dst,
                          const float* __restrict__ ew, int* __restrict__ cursor,
                          int* __restrict__ esrc, float* __restrict__ ew2) {
    int e = blockIdx.x * blockDim.x + threadIdx.x;
    if (e >= N_EDGES) return;
    int d = dst[e];
    int pos = atomicAdd(&cursor[d], 1);
    esrc[pos] = src[e];
    ew2[pos]  = ew[e];
}

// ---------------- per-node degree -> dinv (no atomics; row is contiguous) ----
__global__ void k_deg(const int* __restrict__ rowptr, const float* __restrict__ ew2,
                      float* __restrict__ dinv) {
    int i = blockIdx.x * blockDim.x + threadIdx.x;
    if (i >= N_NODES) return;
    int p1 = rowptr[i + 1];
    float s = 1.0f;                         // self-loop weight
    for (int p = rowptr[i]; p < p1; ++p) s += ew2[p];
    dinv[i] = rsqrtf(s);
}

// ---------------- per-node edge norms ----------------
__global__ void k_norm(const int* __restrict__ rowptr, const int* __restrict__ esrc,
                       const float* __restrict__ ew2, const float* __restrict__ dinv,
                       float* __restrict__ enorm) {
    int i = blockIdx.x * blockDim.x + threadIdx.x;
    if (i >= N_NODES) return;
    float di = dinv[i];
    int p  = rowptr[i];
    int p1 = rowptr[i + 1];
    for (; p + 4 <= p1; p += 4) {
        int s0 = esrc[p], s1 = esrc[p+1], s2 = esrc[p+2], s3 = esrc[p+3];
        float d0 = dinv[s0], d1 = dinv[s1], d2 = dinv[s2], d3 = dinv[s3];
        enorm[p]   = d0 * ew2[p]   * di;
        enorm[p+1] = d1 * ew2[p+1] * di;
        enorm[p+2] = d2 * ew2[p+2] * di;
        enorm[p+3] = d3 * ew2[p+3] * di;
    }
    for (; p < p1; ++p) enorm[p] = dinv[esrc[p]] * ew2[p] * di;
}

// ---------------- GEMM: Y[M,128] = X[M,128] @ W[128,128] ----------------
__global__ __launch_bounds__(256) void k_gemm128(const float* __restrict__ X,
                                                 const float* __restrict__ W,
                                                 float* __restrict__ Y, int M) {
    __shared__ float Wl[128][128];  // 64 KiB
    __shared__ float Xl[32][128];   // 16 KiB
    int t = threadIdx.x;
    for (int i = t; i < 4096; i += 256)
        ((float4*)Wl)[i] = ((const float4*)W)[i];

    int tc = t & 31;   // cols tc*4 .. tc*4+3
    int tr = t >> 5;   // rows tr*4 .. tr*4+3
    for (int g = blockIdx.x; g * 32 < M; g += gridDim.x) {
        int row0 = g * 32;
        __syncthreads();
        for (int i = t; i < 1024; i += 256) {   // 32 rows * 32 float4
            int lr = i >> 5, k4 = i & 31;
            int r = row0 + lr;
            float4 v = make_float4(0.f, 0.f, 0.f, 0.f);
            if (r < M) v = ((const float4*)(X + (size_t)r * 128))[k4];
            ((float4*)&Xl[lr][0])[k4] = v;
        }
        __syncthreads();
        float4 a0 = make_float4(0.f,0.f,0.f,0.f);
        float4 a1 = a0, a2 = a0, a3 = a0;
        int r0 = tr * 4;
#pragma unroll 8
        for (int kc = 0; kc < 32; ++kc) {
            float4 x0 = ((float4*)&Xl[r0 + 0][0])[kc];
            float4 x1 = ((float4*)&Xl[r0 + 1][0])[kc];
            float4 x2 = ((float4*)&Xl[r0 + 2][0])[kc];
            float4 x3 = ((float4*)&Xl[r0 + 3][0])[kc];
            float4 w0 = ((float4*)&Wl[kc * 4 + 0][0])[tc];
            float4 w1 = ((float4*)&Wl[kc * 4 + 1][0])[tc];
            float4 w2 = ((float4*)&Wl[kc * 4 + 2][0])[tc];
            float4 w3 = ((float4*)&Wl[kc * 4 + 3][0])[tc];
#define FMA4(A, XV)                                                        \
            A.x += XV.x*w0.x + XV.y*w1.x + XV.z*w2.x + XV.w*w3.x;          \
            A.y += XV.x*w0.y + XV.y*w1.y + XV.z*w2.y + XV.w*w3.y;          \
            A.z += XV.x*w0.z + XV.y*w1.z + XV.z*w2.z + XV.w*w3.z;          \
            A.w += XV.x*w0.w + XV.y*w1.w + XV.z*w2.w + XV.w*w3.w;
            FMA4(a0, x0) FMA4(a1, x1) FMA4(a2, x2) FMA4(a3, x3)
#undef FMA4
        }
        int gr = row0 + r0;
        if (gr + 3 < M) {
            ((float4*)(Y + (size_t)(gr+0) * 128))[tc] = a0;
            ((float4*)(Y + (size_t)(gr+1) * 128))[tc] = a1;
            ((float4*)(Y + (size_t)(gr+2) * 128))[tc] = a2;
            ((float4*)(Y + (size_t)(gr+3) * 128))[tc] = a3;
        } else {
            if (gr+0 < M) ((float4*)(Y + (size_t)(gr+0) * 128))[tc] = a0;
            if (gr+1 < M) ((float4*)(Y + (size_t)(gr+1) * 128))[tc] = a1;
            if (gr+2 < M) ((float4*)(Y + (size_t)(gr+2) * 128))[tc] = a2;
            if (gr+3 < M) ((float4*)(Y + (size_t)(gr+3) * 128))[tc] = a3;
        }
    }
}

// ---------------- aggregation: one wave per node, 8-deep gather pipeline ----------------
template <int RELU>
__global__ __launch_bounds__(256) void k_agg(const float* __restrict__ h,
                                             const int* __restrict__ rowptr,
                                             const int* __restrict__ esrc,
                                             const float* __restrict__ enorm,
                                             const float* __restrict__ dinv,
                                             const float* __restrict__ bias,
                                             float* __restrict__ out) {
    int wid  = (blockIdx.x * blockDim.x + threadIdx.x) >> 6;  // node
    int lane = threadIdx.x & 63;
    if (wid >= N_NODES) return;
    float di  = dinv[wid];
    float di2 = di * di;
    float2 acc = ((const float2*)(h + (size_t)wid * 128))[lane];
    acc.x *= di2; acc.y *= di2;                       // self-loop term
    int p  = rowptr[wid];
    int p1 = rowptr[wid + 1];
    // 8-wide software pipeline: 8 outstanding 512B row-gathers per wave
    for (; p + 8 <= p1; p += 8) {
        int   s0 = esrc[p],   s1 = esrc[p+1], s2 = esrc[p+2], s3 = esrc[p+3];
        int   s4 = esrc[p+4], s5 = esrc[p+5], s6 = esrc[p+6], s7 = esrc[p+7];
        float w0 = enorm[p],   w1 = enorm[p+1], w2 = enorm[p+2], w3 = enorm[p+3];
        float w4 = enorm[p+4], w5 = enorm[p+5], w6 = enorm[p+6], w7 = enorm[p+7];
        float2 v0 = ((const float2*)(h + (size_t)s0 * 128))[lane];
        float2 v1 = ((const float2*)(h + (size_t)s1 * 128))[lane];
        float2 v2 = ((const float2*)(h + (size_t)s2 * 128))[lane];
        float2 v3 = ((const float2*)(h + (size_t)s3 * 128))[lane];
        float2 v4 = ((const float2*)(h + (size_t)s4 * 128))[lane];
        float2 v5 = ((const float2*)(h + (size_t)s5 * 128))[lane];
        float2 v6 = ((const float2*)(h + (size_t)s6 * 128))[lane];
        float2 v7 = ((const float2*)(h + (size_t)s7 * 128))[lane];
        acc.x += w0*v0.x + w1*v1.x + w2*v2.x + w3*v3.x
               + w4*v4.x + w5*v5.x + w6*v6.x + w7*v7.x;
        acc.y += w0*v0.y + w1*v1.y + w2*v2.y + w3*v3.y
               + w4*v4.y + w5*v5.y + w6*v6.y + w7*v7.y;
    }
    for (; p + 4 <= p1; p += 4) {
        int   s0 = esrc[p],  s1 = esrc[p+1], s2 = esrc[p+2], s3 = esrc[p+3];
        float w0 = enorm[p], w1 = enorm[p+1], w2 = enorm[p+2], w3 = enorm[p+3];
        float2 v0 = ((const float2*)(h + (size_t)s0 * 128))[lane];
        float2 v1 = ((const float2*)(h + (size_t)s1 * 128))[lane];
        float2 v2 = ((const float2*)(h + (size_t)s2 * 128))[lane];
        float2 v3 = ((const float2*)(h + (size_t)s3 * 128))[lane];
        acc.x += w0*v0.x + w1*v1.x + w2*v2.x + w3*v3.x;
        acc.y += w0*v0.y + w1*v1.y + w2*v2.y + w3*v3.y;
    }
    for (; p < p1; ++p) {
        int   s = esrc[p];
        float w = enorm[p];
        float2 hv = ((const float2*)(h + (size_t)s * 128))[lane];
        acc.x += w * hv.x;
        acc.y += w * hv.y;
    }
    float2 bv = ((const float2*)bias)[lane];
    acc.x += bv.x; acc.y += bv.y;
    if (RELU) { acc.x = fmaxf(acc.x, 0.f); acc.y = fmaxf(acc.y, 0.f); }
    ((float2*)(out + (size_t)wid * 128))[lane] = acc;
}

// ---------------- final: out[N,10] = H[N,128] @ Wc[128,10] + bc ----------------
__global__ __launch_bounds__(256) void k_final(const float* __restrict__ H,
                                               const float* __restrict__ Wc,
                                               const float* __restrict__ bc,
                                               float* __restrict__ out) {
    int wid  = (blockIdx.x * blockDim.x + threadIdx.x) >> 6;
    int lane = threadIdx.x & 63;
    if (wid >= N_NODES) return;
    float2 hv = ((const float2*)(H + (size_t)wid * 128))[lane];
    int k0 = 2 * lane;
    float acc[NC];
#pragma unroll
    for (int c = 0; c < NC; ++c)
        acc[c] = hv.x * Wc[k0 * NC + c] + hv.y * Wc[(k0 + 1) * NC + c];
#pragma unroll
    for (int off = 32; off; off >>= 1)
#pragma unroll
        for (int c = 0; c < NC; ++c)
            acc[c] += __shfl_xor(acc[c], off, 64);
    if (lane < NC) out[(size_t)wid * NC + lane] = acc[lane] + bc[lane];
}

extern "C" void kernel_launch(void* const* d_in, const int* in_sizes, int n_in,
                              void* d_out, int out_size, void* d_ws, size_t ws_size,
                              hipStream_t stream) {
    const float* x   = (const float*)d_in[0];
    const int*   ei  = (const int*)d_in[1];
    const float* ew  = (const float*)d_in[2];
    const float* W1  = (const float*)d_in[3];
    const float* b1  = (const float*)d_in[4];
    const float* W2  = (const float*)d_in[5];
    const float* b2  = (const float*)d_in[6];
    const float* Wc  = (const float*)d_in[7];
    const float* bc  = (const float*)d_in[8];
    float*       out = (float*)d_out;

    const int* src = ei;
    const int* dst = ei + N_EDGES;

    size_t off = 0;
    auto carve = [&](size_t bytes) {
        void* p = (char*)d_ws + off;
        off += (bytes + 255) & ~(size_t)255;
        return p;
    };
    float* h      = (float*)carve((size_t)N_NODES * 128 * 4);
    float* agg    = (float*)carve((size_t)N_NODES * 128 * 4);
    float* dinv   = (float*)carve((size_t)N_NODES * 4);
    int*   cnt    = (int*)carve((size_t)N_NODES * 4);
    int*   rowptr = (int*)carve((size_t)(N_NODES + 1) * 4);
    int*   cursor = (int*)carve((size_t)N_NODES * 4);
    int*   bsum   = (int*)carve(256 * 4);
    int*   esrc   = (int*)carve((size_t)N_EDGES * 4);
    float* ew2    = (float*)carve((size_t)N_EDGES * 4);
    float* enorm  = (float*)carve((size_t)N_EDGES * 4);
    (void)ws_size; (void)n_in; (void)in_sizes; (void)out_size;

    hipMemsetAsync(cnt, 0, (size_t)N_NODES * 4, stream);

    int eb = (N_EDGES + 255) / 256;
    int nb = (N_NODES + 255) / 256;

    // CSR build (no float atomics anywhere)
    k_count<<<eb, 256, 0, stream>>>(dst, cnt);
    k_scan1<<<nb, 256, 0, stream>>>(cnt, rowptr, bsum, N_NODES);
    k_scan2<<<1, 256, 0, stream>>>(bsum, nb);
    k_scan3<<<nb, 256, 0, stream>>>(rowptr, bsum, cursor, N_NODES);
    k_scatter<<<eb, 256, 0, stream>>>(src, dst, ew, cursor, esrc, ew2);
    k_deg<<<nb, 256, 0, stream>>>(rowptr, ew2, dinv);
    k_norm<<<nb, 256, 0, stream>>>(rowptr, esrc, ew2, dinv, enorm);

    // layer 1
    k_gemm128<<<512, 256, 0, stream>>>(x, W1, h, N_NODES);
    k_agg<1><<<(N_NODES + 3) / 4, 256, 0, stream>>>(h, rowptr, esrc, enorm, dinv, b1, agg);
    // layer 2
    k_gemm128<<<512, 256, 0, stream>>>(agg, W2, h, N_NODES);
    k_agg<1><<<(N_NODES + 3) / 4, 256, 0, stream>>>(h, rowptr, esrc, enorm, dinv, b2, agg);
    // classifier
    k_final<<<(N_NODES + 3) / 4, 256, 0, stream>>>(agg, Wc, bc, out);
}

// Round 4
// 210.831 us; speedup vs baseline: 1.6818x; 1.3760x over previous
//
#include <hip/hip_runtime.h>
#include <hip/hip_bf16.h>

#define N_NODES 50000
#define N_EDGES 600000
#define NC 10

__device__ __forceinline__ unsigned short f2bf(float f) {
    unsigned u = __float_as_uint(f);
    u += 0x7fff + ((u >> 16) & 1);           // round-to-nearest-even
    return (unsigned short)(u >> 16);
}
__device__ __forceinline__ float bf2f(unsigned short s) {
    return __uint_as_float((unsigned)s << 16);
}

// ---------------- pass 1: count + per-edge ordinal (1 atomic per edge) ------
__global__ void k_count(const int* __restrict__ dst, int* __restrict__ cnt,
                        int* __restrict__ ord) {
    int e = blockIdx.x * blockDim.x + threadIdx.x;
    if (e >= N_EDGES) return;
    ord[e] = atomicAdd(&cnt[dst[e]], 1);
}

// ---------------- exclusive scan (3 kernels) ----------------
__global__ void k_scan1(const int* __restrict__ cnt, int* __restrict__ rowptr,
                        int* __restrict__ bsum, int n) {
    __shared__ int sh[256];
    int t = threadIdx.x;
    int i = blockIdx.x * 256 + t;
    int v = (i < n) ? cnt[i] : 0;
    sh[t] = v;
    __syncthreads();
    for (int off = 1; off < 256; off <<= 1) {
        int x = 0;
        if (t >= off) x = sh[t - off];
        __syncthreads();
        sh[t] += x;
        __syncthreads();
    }
    if (i < n) rowptr[i] = sh[t] - v;
    if (t == 255) bsum[blockIdx.x] = sh[255];
}

__global__ void k_scan2(int* __restrict__ bsum, int nb) {
    __shared__ int sh[256];
    int t = threadIdx.x;
    int v = (t < nb) ? bsum[t] : 0;
    sh[t] = v;
    __syncthreads();
    for (int off = 1; off < 256; off <<= 1) {
        int x = 0;
        if (t >= off) x = sh[t - off];
        __syncthreads();
        sh[t] += x;
        __syncthreads();
    }
    if (t < nb) bsum[t] = sh[t] - v;
}

__global__ void k_scan3(int* __restrict__ rowptr, const int* __restrict__ bsum, int n) {
    int t = threadIdx.x;
    int i = blockIdx.x * 256 + t;
    if (i < n) rowptr[i] += bsum[blockIdx.x];
    if (blockIdx.x == 0 && t == 0) rowptr[n] = N_EDGES;
}

// ---------------- pass 2: scatter into CSR (NO atomics) ----------------
__global__ void k_scatter(const int* __restrict__ src, const int* __restrict__ dst,
                          const float* __restrict__ ew, const int* __restrict__ ord,
                          const int* __restrict__ rowptr,
                          int* __restrict__ esrc, float* __restrict__ ew2) {
    int e = blockIdx.x * blockDim.x + threadIdx.x;
    if (e >= N_EDGES) return;
    int pos = rowptr[dst[e]] + ord[e];
    esrc[pos] = src[e];
    ew2[pos]  = ew[e];
}

// ---------------- per-node degree -> dinv ----------------
__global__ void k_deg(const int* __restrict__ rowptr, const float* __restrict__ ew2,
                      float* __restrict__ dinv) {
    int i = blockIdx.x * blockDim.x + threadIdx.x;
    if (i >= N_NODES) return;
    int p1 = rowptr[i + 1];
    float s = 1.0f;
    for (int p = rowptr[i]; p < p1; ++p) s += ew2[p];
    dinv[i] = rsqrtf(s);
}

// ---------------- per-node edge norms ----------------
__global__ void k_norm(const int* __restrict__ rowptr, const int* __restrict__ esrc,
                       const float* __restrict__ ew2, const float* __restrict__ dinv,
                       float* __restrict__ enorm) {
    int i = blockIdx.x * blockDim.x + threadIdx.x;
    if (i >= N_NODES) return;
    float di = dinv[i];
    int p  = rowptr[i];
    int p1 = rowptr[i + 1];
    for (; p + 4 <= p1; p += 4) {
        int s0 = esrc[p], s1 = esrc[p+1], s2 = esrc[p+2], s3 = esrc[p+3];
        float d0 = dinv[s0], d1 = dinv[s1], d2 = dinv[s2], d3 = dinv[s3];
        enorm[p]   = d0 * ew2[p]   * di;
        enorm[p+1] = d1 * ew2[p+1] * di;
        enorm[p+2] = d2 * ew2[p+2] * di;
        enorm[p+3] = d3 * ew2[p+3] * di;
    }
    for (; p < p1; ++p) enorm[p] = dinv[esrc[p]] * ew2[p] * di;
}

// ---------------- GEMM: Yb[M,128](bf16) = X[M,128] @ W[128,128] ----------------
__global__ __launch_bounds__(256) void k_gemm128(const float* __restrict__ X,
                                                 const float* __restrict__ W,
                                                 unsigned short* __restrict__ Yb, int M) {
    __shared__ float Wl[128][128];  // 64 KiB
    __shared__ float Xl[32][128];   // 16 KiB
    int t = threadIdx.x;
    for (int i = t; i < 4096; i += 256)
        ((float4*)Wl)[i] = ((const float4*)W)[i];

    int tc = t & 31;   // cols tc*4 .. tc*4+3
    int tr = t >> 5;   // rows tr*4 .. tr*4+3
    for (int g = blockIdx.x; g * 32 < M; g += gridDim.x) {
        int row0 = g * 32;
        __syncthreads();
        for (int i = t; i < 1024; i += 256) {   // 32 rows * 32 float4
            int lr = i >> 5, k4 = i & 31;
            int r = row0 + lr;
            float4 v = make_float4(0.f, 0.f, 0.f, 0.f);
            if (r < M) v = ((const float4*)(X + (size_t)r * 128))[k4];
            ((float4*)&Xl[lr][0])[k4] = v;
        }
        __syncthreads();
        float4 a0 = make_float4(0.f,0.f,0.f,0.f);
        float4 a1 = a0, a2 = a0, a3 = a0;
        int r0 = tr * 4;
#pragma unroll 8
        for (int kc = 0; kc < 32; ++kc) {
            float4 x0 = ((float4*)&Xl[r0 + 0][0])[kc];
            float4 x1 = ((float4*)&Xl[r0 + 1][0])[kc];
            float4 x2 = ((float4*)&Xl[r0 + 2][0])[kc];
            float4 x3 = ((float4*)&Xl[r0 + 3][0])[kc];
            float4 w0 = ((float4*)&Wl[kc * 4 + 0][0])[tc];
            float4 w1 = ((float4*)&Wl[kc * 4 + 1][0])[tc];
            float4 w2 = ((float4*)&Wl[kc * 4 + 2][0])[tc];
            float4 w3 = ((float4*)&Wl[kc * 4 + 3][0])[tc];
#define FMA4(A, XV)                                                        \
            A.x += XV.x*w0.x + XV.y*w1.x + XV.z*w2.x + XV.w*w3.x;          \
            A.y += XV.x*w0.y + XV.y*w1.y + XV.z*w2.y + XV.w*w3.y;          \
            A.z += XV.x*w0.z + XV.y*w1.z + XV.z*w2.z + XV.w*w3.z;          \
            A.w += XV.x*w0.w + XV.y*w1.w + XV.z*w2.w + XV.w*w3.w;
            FMA4(a0, x0) FMA4(a1, x1) FMA4(a2, x2) FMA4(a3, x3)
#undef FMA4
        }
        int gr = row0 + r0;
#define WBF(A, R)                                                              \
        if ((R) < M) {                                                         \
            ushort4 o;                                                         \
            o.x = f2bf(A.x); o.y = f2bf(A.y); o.z = f2bf(A.z); o.w = f2bf(A.w);\
            ((ushort4*)(Yb + (size_t)(R) * 128))[tc] = o;                      \
        }
        WBF(a0, gr+0) WBF(a1, gr+1) WBF(a2, gr+2) WBF(a3, gr+3)
#undef WBF
    }
}

// ---------------- aggregation: one wave per node, bf16 gather (256B rows) ----
// MODE 0: out = relu(agg + bias), full 128-float row (feeds GEMM2)
// MODE 1: fused classifier: r = relu(agg + bias); out = r @ Wc + bc (10 floats)
template <int MODE>
__global__ __launch_bounds__(256) void k_agg(const unsigned* __restrict__ hb,
                                             const int* __restrict__ rowptr,
                                             const int* __restrict__ esrc,
                                             const float* __restrict__ enorm,
                                             const float* __restrict__ dinv,
                                             const float* __restrict__ bias,
                                             const float* __restrict__ Wc,
                                             const float* __restrict__ bc,
                                             float* __restrict__ out) {
    int wid  = (blockIdx.x * blockDim.x + threadIdx.x) >> 6;  // node
    int lane = threadIdx.x & 63;
    if (wid >= N_NODES) return;
    float di  = dinv[wid];
    float di2 = di * di;
    unsigned sv = hb[(size_t)wid * 64 + lane];
    float2 acc;
    acc.x = bf2f((unsigned short)(sv & 0xffff)) * di2;
    acc.y = bf2f((unsigned short)(sv >> 16)) * di2;
    int p  = rowptr[wid];
    int p1 = rowptr[wid + 1];
    for (; p + 8 <= p1; p += 8) {
        int   s0 = esrc[p],   s1 = esrc[p+1], s2 = esrc[p+2], s3 = esrc[p+3];
        int   s4 = esrc[p+4], s5 = esrc[p+5], s6 = esrc[p+6], s7 = esrc[p+7];
        float w0 = enorm[p],   w1 = enorm[p+1], w2 = enorm[p+2], w3 = enorm[p+3];
        float w4 = enorm[p+4], w5 = enorm[p+5], w6 = enorm[p+6], w7 = enorm[p+7];
        unsigned v0 = hb[(size_t)s0 * 64 + lane];
        unsigned v1 = hb[(size_t)s1 * 64 + lane];
        unsigned v2 = hb[(size_t)s2 * 64 + lane];
        unsigned v3 = hb[(size_t)s3 * 64 + lane];
        unsigned v4 = hb[(size_t)s4 * 64 + lane];
        unsigned v5 = hb[(size_t)s5 * 64 + lane];
        unsigned v6 = hb[(size_t)s6 * 64 + lane];
        unsigned v7 = hb[(size_t)s7 * 64 + lane];
#define ACC(W, V)                                                   \
        acc.x += (W) * bf2f((unsigned short)((V) & 0xffff));        \
        acc.y += (W) * bf2f((unsigned short)((V) >> 16));
        ACC(w0,v0) ACC(w1,v1) ACC(w2,v2) ACC(w3,v3)
        ACC(w4,v4) ACC(w5,v5) ACC(w6,v6) ACC(w7,v7)
    }
    for (; p + 4 <= p1; p += 4) {
        int   s0 = esrc[p],  s1 = esrc[p+1], s2 = esrc[p+2], s3 = esrc[p+3];
        float w0 = enorm[p], w1 = enorm[p+1], w2 = enorm[p+2], w3 = enorm[p+3];
        unsigned v0 = hb[(size_t)s0 * 64 + lane];
        unsigned v1 = hb[(size_t)s1 * 64 + lane];
        unsigned v2 = hb[(size_t)s2 * 64 + lane];
        unsigned v3 = hb[(size_t)s3 * 64 + lane];
        ACC(w0,v0) ACC(w1,v1) ACC(w2,v2) ACC(w3,v3)
    }
    for (; p < p1; ++p) {
        float w = enorm[p];
        unsigned v = hb[(size_t)esrc[p] * 64 + lane];
        ACC(w,v)
    }
#undef ACC
    float2 bv = ((const float2*)bias)[lane];
    acc.x = fmaxf(acc.x + bv.x, 0.f);
    acc.y = fmaxf(acc.y + bv.y, 0.f);
    if (MODE == 0) {
        ((float2*)(out + (size_t)wid * 128))[lane] = acc;
    } else {
        int k0 = 2 * lane;
        float r[NC];
#pragma unroll
        for (int c = 0; c < NC; ++c)
            r[c] = acc.x * Wc[k0 * NC + c] + acc.y * Wc[(k0 + 1) * NC + c];
#pragma unroll
        for (int off = 32; off; off >>= 1)
#pragma unroll
            for (int c = 0; c < NC; ++c)
                r[c] += __shfl_xor(r[c], off, 64);
        if (lane < NC) out[(size_t)wid * NC + lane] = r[lane] + bc[lane];
    }
}

extern "C" void kernel_launch(void* const* d_in, const int* in_sizes, int n_in,
                              void* d_out, int out_size, void* d_ws, size_t ws_size,
                              hipStream_t stream) {
    const float* x   = (const float*)d_in[0];
    const int*   ei  = (const int*)d_in[1];
    const float* ew  = (const float*)d_in[2];
    const float* W1  = (const float*)d_in[3];
    const float* b1  = (const float*)d_in[4];
    const float* W2  = (const float*)d_in[5];
    const float* b2  = (const float*)d_in[6];
    const float* Wc  = (const float*)d_in[7];
    const float* bc  = (const float*)d_in[8];
    float*       out = (float*)d_out;

    const int* src = ei;
    const int* dst = ei + N_EDGES;

    size_t off = 0;
    auto carve = [&](size_t bytes) {
        void* p = (char*)d_ws + off;
        off += (bytes + 255) & ~(size_t)255;
        return p;
    };
    unsigned short* hb   = (unsigned short*)carve((size_t)N_NODES * 128 * 2); // bf16 h
    float* agg    = (float*)carve((size_t)N_NODES * 128 * 4);
    float* dinv   = (float*)carve((size_t)N_NODES * 4);
    int*   cnt    = (int*)carve((size_t)N_NODES * 4);
    int*   rowptr = (int*)carve((size_t)(N_NODES + 1) * 4);
    int*   bsum   = (int*)carve(256 * 4);
    int*   ord    = (int*)carve((size_t)N_EDGES * 4);
    int*   esrc   = (int*)carve((size_t)N_EDGES * 4);
    float* ew2    = (float*)carve((size_t)N_EDGES * 4);
    float* enorm  = (float*)carve((size_t)N_EDGES * 4);
    (void)ws_size; (void)n_in; (void)in_sizes; (void)out_size;

    hipMemsetAsync(cnt, 0, (size_t)N_NODES * 4, stream);

    int eb = (N_EDGES + 255) / 256;
    int nb = (N_NODES + 255) / 256;

    // CSR build: one atomic pass + scan + atomic-free scatter
    k_count<<<eb, 256, 0, stream>>>(dst, cnt, ord);
    k_scan1<<<nb, 256, 0, stream>>>(cnt, rowptr, bsum, N_NODES);
    k_scan2<<<1, 256, 0, stream>>>(bsum, nb);
    k_scan3<<<nb, 256, 0, stream>>>(rowptr, bsum, N_NODES);
    k_scatter<<<eb, 256, 0, stream>>>(src, dst, ew, ord, rowptr, esrc, ew2);
    k_deg<<<nb, 256, 0, stream>>>(rowptr, ew2, dinv);
    k_norm<<<nb, 256, 0, stream>>>(rowptr, esrc, ew2, dinv, enorm);

    // layer 1
    k_gemm128<<<512, 256, 0, stream>>>(x, W1, hb, N_NODES);
    k_agg<0><<<(N_NODES + 3) / 4, 256, 0, stream>>>((const unsigned*)hb, rowptr, esrc,
                                                    enorm, dinv, b1, Wc, bc, agg);
    // layer 2 + fused classifier
    k_gemm128<<<512, 256, 0, stream>>>(agg, W2, hb, N_NODES);
    k_agg<1><<<(N_NODES + 3) / 4, 256, 0, stream>>>((const unsigned*)hb, rowptr, esrc,
                                                    enorm, dinv, b2, Wc, bc, out);
}

// Round 5
// 205.580 us; speedup vs baseline: 1.7247x; 1.0255x over previous
//
#include <hip/hip_runtime.h>
#include <hip/hip_bf16.h>

#define N_NODES 50000
#define N_EDGES 600000
#define NC 10

__device__ __forceinline__ unsigned short f2bf(float f) {
    unsigned u = __float_as_uint(f);
    u += 0x7fff + ((u >> 16) & 1);           // round-to-nearest-even
    return (unsigned short)(u >> 16);
}
__device__ __forceinline__ float bf2f(unsigned short s) {
    return __uint_as_float((unsigned)s << 16);
}

// ---------------- zero helper (rocclr fillBuffer is ~45us in-graph) ---------
__global__ void k_zero(int4* __restrict__ p, int n4) {
    int i = blockIdx.x * blockDim.x + threadIdx.x;
    if (i < n4) p[i] = make_int4(0, 0, 0, 0);
}

// ---------------- pass 1: count + per-edge ordinal (1 atomic per edge) ------
__global__ void k_count(const int* __restrict__ dst, int* __restrict__ cnt,
                        int* __restrict__ ord) {
    int e = blockIdx.x * blockDim.x + threadIdx.x;
    if (e >= N_EDGES) return;
    ord[e] = atomicAdd(&cnt[dst[e]], 1);
}

// ---------------- exclusive scan (3 kernels) ----------------
__global__ void k_scan1(const int* __restrict__ cnt, int* __restrict__ rowptr,
                        int* __restrict__ bsum, int n) {
    __shared__ int sh[256];
    int t = threadIdx.x;
    int i = blockIdx.x * 256 + t;
    int v = (i < n) ? cnt[i] : 0;
    sh[t] = v;
    __syncthreads();
    for (int off = 1; off < 256; off <<= 1) {
        int x = 0;
        if (t >= off) x = sh[t - off];
        __syncthreads();
        sh[t] += x;
        __syncthreads();
    }
    if (i < n) rowptr[i] = sh[t] - v;
    if (t == 255) bsum[blockIdx.x] = sh[255];
}

__global__ void k_scan2(int* __restrict__ bsum, int nb) {
    __shared__ int sh[256];
    int t = threadIdx.x;
    int v = (t < nb) ? bsum[t] : 0;
    sh[t] = v;
    __syncthreads();
    for (int off = 1; off < 256; off <<= 1) {
        int x = 0;
        if (t >= off) x = sh[t - off];
        __syncthreads();
        sh[t] += x;
        __syncthreads();
    }
    if (t < nb) bsum[t] = sh[t] - v;
}

__global__ void k_scan3(int* __restrict__ rowptr, const int* __restrict__ bsum, int n) {
    int t = threadIdx.x;
    int i = blockIdx.x * 256 + t;
    if (i < n) rowptr[i] += bsum[blockIdx.x];
    if (blockIdx.x == 0 && t == 0) rowptr[n] = N_EDGES;
}

// ---------------- pass 2: scatter into CSR (NO atomics) ----------------
__global__ void k_scatter(const int* __restrict__ src, const int* __restrict__ dst,
                          const float* __restrict__ ew, const int* __restrict__ ord,
                          const int* __restrict__ rowptr,
                          int* __restrict__ esrc, float* __restrict__ ew2) {
    int e = blockIdx.x * blockDim.x + threadIdx.x;
    if (e >= N_EDGES) return;
    int pos = rowptr[dst[e]] + ord[e];
    esrc[pos] = src[e];
    ew2[pos]  = ew[e];
}

// ---------------- per-node degree -> dinv ----------------
__global__ void k_deg(const int* __restrict__ rowptr, const float* __restrict__ ew2,
                      float* __restrict__ dinv) {
    int i = blockIdx.x * blockDim.x + threadIdx.x;
    if (i >= N_NODES) return;
    int p1 = rowptr[i + 1];
    float s = 1.0f;
    for (int p = rowptr[i]; p < p1; ++p) s += ew2[p];
    dinv[i] = rsqrtf(s);
}

// ---------------- per-node edge norms ----------------
__global__ void k_norm(const int* __restrict__ rowptr, const int* __restrict__ esrc,
                       const float* __restrict__ ew2, const float* __restrict__ dinv,
                       float* __restrict__ enorm) {
    int i = blockIdx.x * blockDim.x + threadIdx.x;
    if (i >= N_NODES) return;
    float di = dinv[i];
    int p  = rowptr[i];
    int p1 = rowptr[i + 1];
    for (; p + 4 <= p1; p += 4) {
        int s0 = esrc[p], s1 = esrc[p+1], s2 = esrc[p+2], s3 = esrc[p+3];
        float d0 = dinv[s0], d1 = dinv[s1], d2 = dinv[s2], d3 = dinv[s3];
        enorm[p]   = d0 * ew2[p]   * di;
        enorm[p+1] = d1 * ew2[p+1] * di;
        enorm[p+2] = d2 * ew2[p+2] * di;
        enorm[p+3] = d3 * ew2[p+3] * di;
    }
    for (; p < p1; ++p) enorm[p] = dinv[esrc[p]] * ew2[p] * di;
}

// ---------------- GEMM: Yb[M,128](bf16) = X[M,128] @ W[128,128] ----------------
// Block: 64 rows x 64 cols (col-split across 2 blocks). LDS 48KB -> 3 blocks/CU.
// X staged TRANSPOSED (XlT[k][r], XOR-swizzled) so inner loop is 2x ds_read_b128
// per 16 FMAs. K chunked by 64.
__global__ __launch_bounds__(256) void k_gemm128(const float* __restrict__ X,
                                                 const float* __restrict__ W,
                                                 unsigned short* __restrict__ Yb, int M) {
    __shared__ float Wl[128][64];   // 32 KiB
    __shared__ float XlT[64 * 64];  // 16 KiB, [k][r] XOR-swizzled
    int t = threadIdx.x;
    int row0 = (blockIdx.x >> 1) * 64;
    int bc   = (blockIdx.x & 1) * 64;
    float* ws = &Wl[0][0];
    float* xs = &XlT[0];

    // stage W cols bc..bc+63 (all 128 k rows)
    for (int i = t; i < 2048; i += 256) {
        int k = i >> 4, c4 = i & 15;
        *(float4*)(ws + k * 64 + c4 * 4) = *(const float4*)(W + (size_t)k * 128 + bc + c4 * 4);
    }

    const int r0 = (t >> 4) * 4;   // output rows r0..r0+3 (local)
    const int c0 = (t & 15) * 4;   // output cols c0..c0+3 (local)
    float4 a0 = make_float4(0.f,0.f,0.f,0.f);
    float4 a1 = a0, a2 = a0, a3 = a0;

    const int sr = t >> 4;         // staging row base 0..15
    const int kq = t & 15;         // staging k-quad 0..15
    const int swz = (kq & 3) << 3; // write-side XOR granule

    for (int kb = 0; kb < 128; kb += 64) {
        __syncthreads();           // Wl ready (iter 0) / XlT consumed (iter 1)
#pragma unroll
        for (int it = 0; it < 4; ++it) {
            int r = sr + it * 16;
            int grow = row0 + r;
            float4 v = make_float4(0.f, 0.f, 0.f, 0.f);
            if (grow < M) v = *(const float4*)(X + (size_t)grow * 128 + kb + kq * 4);
            int rs = r ^ swz;
            int k0 = kq * 4;
            xs[(k0 + 0) * 64 + rs] = v.x;
            xs[(k0 + 1) * 64 + rs] = v.y;
            xs[(k0 + 2) * 64 + rs] = v.z;
            xs[(k0 + 3) * 64 + rs] = v.w;
        }
        __syncthreads();
#pragma unroll 8
        for (int k = 0; k < 64; ++k) {
            int g = ((k >> 2) & 3) << 3;
            float4 xv = *(const float4*)(xs + k * 64 + (r0 ^ g));
            float4 wv = *(const float4*)(ws + (kb + k) * 64 + c0);
            a0.x += xv.x*wv.x; a0.y += xv.x*wv.y; a0.z += xv.x*wv.z; a0.w += xv.x*wv.w;
            a1.x += xv.y*wv.x; a1.y += xv.y*wv.y; a1.z += xv.y*wv.z; a1.w += xv.y*wv.w;
            a2.x += xv.z*wv.x; a2.y += xv.z*wv.y; a2.z += xv.z*wv.z; a2.w += xv.z*wv.w;
            a3.x += xv.w*wv.x; a3.y += xv.w*wv.y; a3.z += xv.w*wv.z; a3.w += xv.w*wv.w;
        }
    }

    int gr = row0 + r0;
#define WBF(A, R)                                                              \
    if ((R) < M) {                                                             \
        ushort4 o;                                                             \
        o.x = f2bf(A.x); o.y = f2bf(A.y); o.z = f2bf(A.z); o.w = f2bf(A.w);    \
        *(ushort4*)(Yb + (size_t)(R) * 128 + bc + c0) = o;                     \
    }
    WBF(a0, gr+0) WBF(a1, gr+1) WBF(a2, gr+2) WBF(a3, gr+3)
#undef WBF
}

// ---------------- aggregation: one wave per node, bf16 gather (256B rows) ----
// MODE 0: out = relu(agg + bias), full 128-float row (feeds GEMM2)
// MODE 1: fused classifier: r = relu(agg + bias); out = r @ Wc + bc (10 floats)
template <int MODE>
__global__ __launch_bounds__(256) void k_agg(const unsigned* __restrict__ hb,
                                             const int* __restrict__ rowptr,
                                             const int* __restrict__ esrc,
                                             const float* __restrict__ enorm,
                                             const float* __restrict__ dinv,
                                             const float* __restrict__ bias,
                                             const float* __restrict__ Wc,
                                             const float* __restrict__ bc,
                                             float* __restrict__ out) {
    int wid  = (blockIdx.x * blockDim.x + threadIdx.x) >> 6;  // node
    int lane = threadIdx.x & 63;
    if (wid >= N_NODES) return;
    float di  = dinv[wid];
    float di2 = di * di;
    unsigned sv = hb[(size_t)wid * 64 + lane];
    float2 acc;
    acc.x = bf2f((unsigned short)(sv & 0xffff)) * di2;
    acc.y = bf2f((unsigned short)(sv >> 16)) * di2;
    int p  = rowptr[wid];
    int p1 = rowptr[wid + 1];
    for (; p + 8 <= p1; p += 8) {
        int   s0 = esrc[p],   s1 = esrc[p+1], s2 = esrc[p+2], s3 = esrc[p+3];
        int   s4 = esrc[p+4], s5 = esrc[p+5], s6 = esrc[p+6], s7 = esrc[p+7];
        float w0 = enorm[p],   w1 = enorm[p+1], w2 = enorm[p+2], w3 = enorm[p+3];
        float w4 = enorm[p+4], w5 = enorm[p+5], w6 = enorm[p+6], w7 = enorm[p+7];
        unsigned v0 = hb[(size_t)s0 * 64 + lane];
        unsigned v1 = hb[(size_t)s1 * 64 + lane];
        unsigned v2 = hb[(size_t)s2 * 64 + lane];
        unsigned v3 = hb[(size_t)s3 * 64 + lane];
        unsigned v4 = hb[(size_t)s4 * 64 + lane];
        unsigned v5 = hb[(size_t)s5 * 64 + lane];
        unsigned v6 = hb[(size_t)s6 * 64 + lane];
        unsigned v7 = hb[(size_t)s7 * 64 + lane];
#define ACC(W, V)                                                   \
        acc.x += (W) * bf2f((unsigned short)((V) & 0xffff));        \
        acc.y += (W) * bf2f((unsigned short)((V) >> 16));
        ACC(w0,v0) ACC(w1,v1) ACC(w2,v2) ACC(w3,v3)
        ACC(w4,v4) ACC(w5,v5) ACC(w6,v6) ACC(w7,v7)
    }
    for (; p + 4 <= p1; p += 4) {
        int   s0 = esrc[p],  s1 = esrc[p+1], s2 = esrc[p+2], s3 = esrc[p+3];
        float w0 = enorm[p], w1 = enorm[p+1], w2 = enorm[p+2], w3 = enorm[p+3];
        unsigned v0 = hb[(size_t)s0 * 64 + lane];
        unsigned v1 = hb[(size_t)s1 * 64 + lane];
        unsigned v2 = hb[(size_t)s2 * 64 + lane];
        unsigned v3 = hb[(size_t)s3 * 64 + lane];
        ACC(w0,v0) ACC(w1,v1) ACC(w2,v2) ACC(w3,v3)
    }
    for (; p < p1; ++p) {
        float w = enorm[p];
        unsigned v = hb[(size_t)esrc[p] * 64 + lane];
        ACC(w,v)
    }
#undef ACC
    float2 bv = ((const float2*)bias)[lane];
    acc.x = fmaxf(acc.x + bv.x, 0.f);
    acc.y = fmaxf(acc.y + bv.y, 0.f);
    if (MODE == 0) {
        ((float2*)(out + (size_t)wid * 128))[lane] = acc;
    } else {
        int k0 = 2 * lane;
        float r[NC];
#pragma unroll
        for (int c = 0; c < NC; ++c)
            r[c] = acc.x * Wc[k0 * NC + c] + acc.y * Wc[(k0 + 1) * NC + c];
#pragma unroll
        for (int off = 32; off; off >>= 1)
#pragma unroll
            for (int c = 0; c < NC; ++c)
                r[c] += __shfl_xor(r[c], off, 64);
        if (lane < NC) out[(size_t)wid * NC + lane] = r[lane] + bc[lane];
    }
}

extern "C" void kernel_launch(void* const* d_in, const int* in_sizes, int n_in,
                              void* d_out, int out_size, void* d_ws, size_t ws_size,
                              hipStream_t stream) {
    const float* x   = (const float*)d_in[0];
    const int*   ei  = (const int*)d_in[1];
    const float* ew  = (const float*)d_in[2];
    const float* W1  = (const float*)d_in[3];
    const float* b1  = (const float*)d_in[4];
    const float* W2  = (const float*)d_in[5];
    const float* b2  = (const float*)d_in[6];
    const float* Wc  = (const float*)d_in[7];
    const float* bc  = (const float*)d_in[8];
    float*       out = (float*)d_out;

    const int* src = ei;
    const int* dst = ei + N_EDGES;

    size_t off = 0;
    auto carve = [&](size_t bytes) {
        void* p = (char*)d_ws + off;
        off += (bytes + 255) & ~(size_t)255;
        return p;
    };
    unsigned short* hb = (unsigned short*)carve((size_t)N_NODES * 128 * 2); // bf16 h
    float* agg    = (float*)carve((size_t)N_NODES * 128 * 4);
    float* dinv   = (float*)carve((size_t)N_NODES * 4);
    int*   cnt    = (int*)carve((size_t)N_NODES * 4);
    int*   rowptr = (int*)carve((size_t)(N_NODES + 1) * 4);
    int*   bsum   = (int*)carve(256 * 4);
    int*   ord    = (int*)carve((size_t)N_EDGES * 4);
    int*   esrc   = (int*)carve((size_t)N_EDGES * 4);
    float* ew2    = (float*)carve((size_t)N_EDGES * 4);
    float* enorm  = (float*)carve((size_t)N_EDGES * 4);
    (void)ws_size; (void)n_in; (void)in_sizes; (void)out_size;

    int eb = (N_EDGES + 255) / 256;
    int nb = (N_NODES + 255) / 256;

    // CSR build: custom zero + one atomic pass + scan + atomic-free scatter
    k_zero<<<(N_NODES / 4 + 255) / 256, 256, 0, stream>>>((int4*)cnt, N_NODES / 4);
    k_count<<<eb, 256, 0, stream>>>(dst, cnt, ord);
    k_scan1<<<nb, 256, 0, stream>>>(cnt, rowptr, bsum, N_NODES);
    k_scan2<<<1, 256, 0, stream>>>(bsum, nb);
    k_scan3<<<nb, 256, 0, stream>>>(rowptr, bsum, N_NODES);
    k_scatter<<<eb, 256, 0, stream>>>(src, dst, ew, ord, rowptr, esrc, ew2);
    k_deg<<<nb, 256, 0, stream>>>(rowptr, ew2, dinv);
    k_norm<<<nb, 256, 0, stream>>>(rowptr, esrc, ew2, dinv, enorm);

    int gb = ((N_NODES + 63) / 64) * 2;   // 782 row-groups x 2 col-halves
    // layer 1
    k_gemm128<<<gb, 256, 0, stream>>>(x, W1, hb, N_NODES);
    k_agg<0><<<(N_NODES + 3) / 4, 256, 0, stream>>>((const unsigned*)hb, rowptr, esrc,
                                                    enorm, dinv, b1, Wc, bc, agg);
    // layer 2 + fused classifier
    k_gemm128<<<gb, 256, 0, stream>>>(agg, W2, hb, N_NODES);
    k_agg<1><<<(N_NODES + 3) / 4, 256, 0, stream>>>((const unsigned*)hb, rowptr, esrc,
                                                    enorm, dinv, b2, Wc, bc, out);
}

// Round 6
// 198.033 us; speedup vs baseline: 1.7905x; 1.0381x over previous
//
#include <hip/hip_runtime.h>
#include <hip/hip_bf16.h>

#define N_NODES 50000
#define N_EDGES 600000
#define NC 10

__device__ __forceinline__ unsigned short f2bf(float f) {
    unsigned u = __float_as_uint(f);
    u += 0x7fff + ((u >> 16) & 1);           // round-to-nearest-even
    return (unsigned short)(u >> 16);
}

// ---------------- zero helper (rocclr fillBuffer is ~45us in-graph) ---------
__global__ void k_zero(int4* __restrict__ p, int n4) {
    int i = blockIdx.x * blockDim.x + threadIdx.x;
    if (i < n4) p[i] = make_int4(0, 0, 0, 0);
}

// ---------------- pass 1: count + per-edge ordinal (1 atomic per edge) ------
// 4 edges per thread, coalesced int4 IO for dst/ord.
__global__ void k_count(const int4* __restrict__ dst4, int* __restrict__ cnt,
                        int4* __restrict__ ord4) {
    int i = blockIdx.x * blockDim.x + threadIdx.x;
    if (i >= N_EDGES / 4) return;
    int4 d = dst4[i];
    int4 o;
    o.x = atomicAdd(&cnt[d.x], 1);
    o.y = atomicAdd(&cnt[d.y], 1);
    o.z = atomicAdd(&cnt[d.z], 1);
    o.w = atomicAdd(&cnt[d.w], 1);
    ord4[i] = o;
}

// ---------------- exclusive scan (3 kernels) ----------------
__global__ void k_scan1(const int* __restrict__ cnt, int* __restrict__ rowptr,
                        int* __restrict__ bsum, int n) {
    __shared__ int sh[256];
    int t = threadIdx.x;
    int i = blockIdx.x * 256 + t;
    int v = (i < n) ? cnt[i] : 0;
    sh[t] = v;
    __syncthreads();
    for (int off = 1; off < 256; off <<= 1) {
        int x = 0;
        if (t >= off) x = sh[t - off];
        __syncthreads();
        sh[t] += x;
        __syncthreads();
    }
    if (i < n) rowptr[i] = sh[t] - v;
    if (t == 255) bsum[blockIdx.x] = sh[255];
}

__global__ void k_scan2(int* __restrict__ bsum, int nb) {
    __shared__ int sh[256];
    int t = threadIdx.x;
    int v = (t < nb) ? bsum[t] : 0;
    sh[t] = v;
    __syncthreads();
    for (int off = 1; off < 256; off <<= 1) {
        int x = 0;
        if (t >= off) x = sh[t - off];
        __syncthreads();
        sh[t] += x;
        __syncthreads();
    }
    if (t < nb) bsum[t] = sh[t] - v;
}

__global__ void k_scan3(int* __restrict__ rowptr, const int* __restrict__ bsum, int n) {
    int t = threadIdx.x;
    int i = blockIdx.x * 256 + t;
    if (i < n) rowptr[i] += bsum[blockIdx.x];
    if (blockIdx.x == 0 && t == 0) rowptr[n] = N_EDGES;
}

// ---------------- pass 2: scatter into CSR (NO atomics) ----------------
__global__ void k_scatter(const int* __restrict__ src, const int* __restrict__ dst,
                          const float* __restrict__ ew, const int* __restrict__ ord,
                          const int* __restrict__ rowptr,
                          int* __restrict__ esrc, float* __restrict__ ew2) {
    int e = blockIdx.x * blockDim.x + threadIdx.x;
    if (e >= N_EDGES) return;
    int pos = rowptr[dst[e]] + ord[e];
    esrc[pos] = src[e];
    ew2[pos]  = ew[e];
}

// ---------------- per-node degree -> dinv ----------------
__global__ void k_deg(const int* __restrict__ rowptr, const float* __restrict__ ew2,
                      float* __restrict__ dinv) {
    int i = blockIdx.x * blockDim.x + threadIdx.x;
    if (i >= N_NODES) return;
    int p1 = rowptr[i + 1];
    float s = 1.0f;
    for (int p = rowptr[i]; p < p1; ++p) s += ew2[p];
    dinv[i] = rsqrtf(s);
}

// ---------------- per-node edge norms ----------------
__global__ void k_norm(const int* __restrict__ rowptr, const int* __restrict__ esrc,
                       const float* __restrict__ ew2, const float* __restrict__ dinv,
                       float* __restrict__ enorm) {
    int i = blockIdx.x * blockDim.x + threadIdx.x;
    if (i >= N_NODES) return;
    float di = dinv[i];
    int p  = rowptr[i];
    int p1 = rowptr[i + 1];
    for (; p + 4 <= p1; p += 4) {
        int s0 = esrc[p], s1 = esrc[p+1], s2 = esrc[p+2], s3 = esrc[p+3];
        float d0 = dinv[s0], d1 = dinv[s1], d2 = dinv[s2], d3 = dinv[s3];
        enorm[p]   = d0 * ew2[p]   * di;
        enorm[p+1] = d1 * ew2[p+1] * di;
        enorm[p+2] = d2 * ew2[p+2] * di;
        enorm[p+3] = d3 * ew2[p+3] * di;
    }
    for (; p < p1; ++p) enorm[p] = dinv[esrc[p]] * ew2[p] * di;
}

// ---------------- GEMM: Yb[M,128](bf16) = X[M,128] @ W[128,128] ----------------
// Block: 64 rows x 64 cols. LDS 48KB -> 3 blocks/CU. X staged transposed,
// XOR-swizzled; inner loop all ds_read_b128.
__global__ __launch_bounds__(256) void k_gemm128(const float* __restrict__ X,
                                                 const float* __restrict__ W,
                                                 unsigned short* __restrict__ Yb, int M) {
    __shared__ float Wl[128][64];   // 32 KiB
    __shared__ float XlT[64 * 64];  // 16 KiB, [k][r] XOR-swizzled
    int t = threadIdx.x;
    int row0 = (blockIdx.x >> 1) * 64;
    int bc   = (blockIdx.x & 1) * 64;
    float* ws = &Wl[0][0];
    float* xs = &XlT[0];

    for (int i = t; i < 2048; i += 256) {
        int k = i >> 4, c4 = i & 15;
        *(float4*)(ws + k * 64 + c4 * 4) = *(const float4*)(W + (size_t)k * 128 + bc + c4 * 4);
    }

    const int r0 = (t >> 4) * 4;
    const int c0 = (t & 15) * 4;
    float4 a0 = make_float4(0.f,0.f,0.f,0.f);
    float4 a1 = a0, a2 = a0, a3 = a0;

    const int sr = t >> 4;
    const int kq = t & 15;
    const int swz = (kq & 3) << 3;

    for (int kb = 0; kb < 128; kb += 64) {
        __syncthreads();
#pragma unroll
        for (int it = 0; it < 4; ++it) {
            int r = sr + it * 16;
            int grow = row0 + r;
            float4 v = make_float4(0.f, 0.f, 0.f, 0.f);
            if (grow < M) v = *(const float4*)(X + (size_t)grow * 128 + kb + kq * 4);
            int rs = r ^ swz;
            int k0 = kq * 4;
            xs[(k0 + 0) * 64 + rs] = v.x;
            xs[(k0 + 1) * 64 + rs] = v.y;
            xs[(k0 + 2) * 64 + rs] = v.z;
            xs[(k0 + 3) * 64 + rs] = v.w;
        }
        __syncthreads();
#pragma unroll 8
        for (int k = 0; k < 64; ++k) {
            int g = ((k >> 2) & 3) << 3;
            float4 xv = *(const float4*)(xs + k * 64 + (r0 ^ g));
            float4 wv = *(const float4*)(ws + (kb + k) * 64 + c0);
            a0.x += xv.x*wv.x; a0.y += xv.x*wv.y; a0.z += xv.x*wv.z; a0.w += xv.x*wv.w;
            a1.x += xv.y*wv.x; a1.y += xv.y*wv.y; a1.z += xv.y*wv.z; a1.w += xv.y*wv.w;
            a2.x += xv.z*wv.x; a2.y += xv.z*wv.y; a2.z += xv.z*wv.z; a2.w += xv.z*wv.w;
            a3.x += xv.w*wv.x; a3.y += xv.w*wv.y; a3.z += xv.w*wv.z; a3.w += xv.w*wv.w;
        }
    }

    int gr = row0 + r0;
#define WBF(A, R)                                                              \
    if ((R) < M) {                                                             \
        ushort4 o;                                                             \
        o.x = f2bf(A.x); o.y = f2bf(A.y); o.z = f2bf(A.z); o.w = f2bf(A.w);    \
        *(ushort4*)(Yb + (size_t)(R) * 128 + bc + c0) = o;                     \
    }
    WBF(a0, gr+0) WBF(a1, gr+1) WBF(a2, gr+2) WBF(a3, gr+3)
#undef WBF
}

// ---------------- aggregation: one wave/node, scalar edge metadata, 12-deep --
// MODE 0: out = relu(agg + bias), full 128-float row (feeds GEMM2)
// MODE 1: fused classifier: r = relu(agg + bias); out = r @ Wc + bc
template <int MODE>
__global__ __launch_bounds__(256) void k_agg(const unsigned* __restrict__ hb,
                                             const int* __restrict__ rowptr,
                                             const int* __restrict__ esrc,
                                             const float* __restrict__ enorm,
                                             const float* __restrict__ dinv,
                                             const float* __restrict__ bias,
                                             const float* __restrict__ Wc,
                                             const float* __restrict__ bc,
                                             float* __restrict__ out) {
    int wid  = (blockIdx.x * blockDim.x + threadIdx.x) >> 6;  // wave-uniform
    int lane = threadIdx.x & 63;
    if (wid >= N_NODES) return;
    wid = __builtin_amdgcn_readfirstlane(wid);
    // scalar (SGPR) edge-range + metadata loads -> VMEM queue reserved for gathers
    int p  = __builtin_amdgcn_readfirstlane(rowptr[wid]);
    int p1 = __builtin_amdgcn_readfirstlane(rowptr[wid + 1]);
    float di  = dinv[wid];
    float di2 = di * di;
    unsigned sv = hb[(size_t)wid * 64 + lane];
    float2 acc;
    acc.x = __uint_as_float(sv << 16) * di2;
    acc.y = __uint_as_float(sv & 0xffff0000u) * di2;

    while (p + 12 <= p1) {
        int s[12]; float w[12]; unsigned v[12];
#pragma unroll
        for (int i = 0; i < 12; ++i) {
            s[i] = __builtin_amdgcn_readfirstlane(esrc[p + i]);
            w[i] = enorm[p + i];
        }
#pragma unroll
        for (int i = 0; i < 12; ++i) v[i] = hb[(size_t)s[i] * 64 + lane];
#pragma unroll
        for (int i = 0; i < 12; ++i) {
            acc.x += w[i] * __uint_as_float(v[i] << 16);
            acc.y += w[i] * __uint_as_float(v[i] & 0xffff0000u);
        }
        p += 12;
    }
    while (p + 4 <= p1) {
        int s[4]; float w[4]; unsigned v[4];
#pragma unroll
        for (int i = 0; i < 4; ++i) {
            s[i] = __builtin_amdgcn_readfirstlane(esrc[p + i]);
            w[i] = enorm[p + i];
        }
#pragma unroll
        for (int i = 0; i < 4; ++i) v[i] = hb[(size_t)s[i] * 64 + lane];
#pragma unroll
        for (int i = 0; i < 4; ++i) {
            acc.x += w[i] * __uint_as_float(v[i] << 16);
            acc.y += w[i] * __uint_as_float(v[i] & 0xffff0000u);
        }
        p += 4;
    }
    for (; p < p1; ++p) {
        int s = __builtin_amdgcn_readfirstlane(esrc[p]);
        float w = enorm[p];
        unsigned v = hb[(size_t)s * 64 + lane];
        acc.x += w * __uint_as_float(v << 16);
        acc.y += w * __uint_as_float(v & 0xffff0000u);
    }

    float2 bv = ((const float2*)bias)[lane];
    acc.x = fmaxf(acc.x + bv.x, 0.f);
    acc.y = fmaxf(acc.y + bv.y, 0.f);
    if (MODE == 0) {
        ((float2*)(out + (size_t)wid * 128))[lane] = acc;
    } else {
        int k0 = 2 * lane;
        float r[NC];
#pragma unroll
        for (int c = 0; c < NC; ++c)
            r[c] = acc.x * Wc[k0 * NC + c] + acc.y * Wc[(k0 + 1) * NC + c];
#pragma unroll
        for (int off = 32; off; off >>= 1)
#pragma unroll
            for (int c = 0; c < NC; ++c)
                r[c] += __shfl_xor(r[c], off, 64);
        if (lane < NC) out[(size_t)wid * NC + lane] = r[lane] + bc[lane];
    }
}

extern "C" void kernel_launch(void* const* d_in, const int* in_sizes, int n_in,
                              void* d_out, int out_size, void* d_ws, size_t ws_size,
                              hipStream_t stream) {
    const float* x   = (const float*)d_in[0];
    const int*   ei  = (const int*)d_in[1];
    const float* ew  = (const float*)d_in[2];
    const float* W1  = (const float*)d_in[3];
    const float* b1  = (const float*)d_in[4];
    const float* W2  = (const float*)d_in[5];
    const float* b2  = (const float*)d_in[6];
    const float* Wc  = (const float*)d_in[7];
    const float* bc  = (const float*)d_in[8];
    float*       out = (float*)d_out;

    const int* src = ei;
    const int* dst = ei + N_EDGES;

    size_t off = 0;
    auto carve = [&](size_t bytes) {
        void* p = (char*)d_ws + off;
        off += (bytes + 255) & ~(size_t)255;
        return p;
    };
    unsigned short* hb = (unsigned short*)carve((size_t)N_NODES * 128 * 2); // bf16 h
    float* agg    = (float*)carve((size_t)N_NODES * 128 * 4);
    float* dinv   = (float*)carve((size_t)N_NODES * 4);
    int*   cnt    = (int*)carve((size_t)N_NODES * 4);
    int*   rowptr = (int*)carve((size_t)(N_NODES + 1) * 4);
    int*   bsum   = (int*)carve(256 * 4);
    int*   ord    = (int*)carve((size_t)N_EDGES * 4);
    int*   esrc   = (int*)carve((size_t)N_EDGES * 4);
    float* ew2    = (float*)carve((size_t)N_EDGES * 4);
    float* enorm  = (float*)carve((size_t)N_EDGES * 4);
    (void)ws_size; (void)n_in; (void)in_sizes; (void)out_size;

    int eb = (N_EDGES + 255) / 256;
    int nb = (N_NODES + 255) / 256;

    // CSR build
    k_zero<<<(N_NODES / 4 + 255) / 256, 256, 0, stream>>>((int4*)cnt, N_NODES / 4);
    k_count<<<(N_EDGES / 4 + 255) / 256, 256, 0, stream>>>((const int4*)dst, cnt, (int4*)ord);
    k_scan1<<<nb, 256, 0, stream>>>(cnt, rowptr, bsum, N_NODES);
    k_scan2<<<1, 256, 0, stream>>>(bsum, nb);
    k_scan3<<<nb, 256, 0, stream>>>(rowptr, bsum, N_NODES);
    k_scatter<<<eb, 256, 0, stream>>>(src, dst, ew, ord, rowptr, esrc, ew2);
    k_deg<<<nb, 256, 0, stream>>>(rowptr, ew2, dinv);
    k_norm<<<nb, 256, 0, stream>>>(rowptr, esrc, ew2, dinv, enorm);

    int gb = ((N_NODES + 63) / 64) * 2;
    // layer 1
    k_gemm128<<<gb, 256, 0, stream>>>(x, W1, hb, N_NODES);
    k_agg<0><<<(N_NODES + 3) / 4, 256, 0, stream>>>((const unsigned*)hb, rowptr, esrc,
                                                    enorm, dinv, b1, Wc, bc, agg);
    // layer 2 + fused classifier
    k_gemm128<<<gb, 256, 0, stream>>>(agg, W2, hb, N_NODES);
    k_agg<1><<<(N_NODES + 3) / 4, 256, 0, stream>>>((const unsigned*)hb, rowptr, esrc,
                                                    enorm, dinv, b2, Wc, bc, out);
}

// Round 7
// 172.414 us; speedup vs baseline: 2.0565x; 1.1486x over previous
//
#include <hip/hip_runtime.h>
#include <hip/hip_bf16.h>

#define N_NODES 50000
#define N_EDGES 600000
#define NC 10

typedef __attribute__((ext_vector_type(8))) __bf16 bf16x8;
typedef __attribute__((ext_vector_type(4))) float f32x4;

__device__ __forceinline__ unsigned short f2bf(float f) {
    unsigned u = __float_as_uint(f);
    u += 0x7fff + ((u >> 16) & 1);           // round-to-nearest-even
    return (unsigned short)(u >> 16);
}

// ---------------- zero helper ----------------
__global__ void k_zero(int4* __restrict__ p, int n4) {
    int i = blockIdx.x * blockDim.x + threadIdx.x;
    if (i < n4) p[i] = make_int4(0, 0, 0, 0);
}

// ---------------- fp32 -> bf16 convert (x) ----------------
__global__ void k_x2b(const float4* __restrict__ in, ushort4* __restrict__ out, int n4) {
    int i = blockIdx.x * blockDim.x + threadIdx.x;
    if (i >= n4) return;
    float4 v = in[i];
    ushort4 o;
    o.x = f2bf(v.x); o.y = f2bf(v.y); o.z = f2bf(v.z); o.w = f2bf(v.w);
    out[i] = o;
}

// ---------------- W[k][n] fp32 -> Wt[n][k] bf16 ----------------
__global__ void k_wt(const float* __restrict__ W, unsigned short* __restrict__ Wt) {
    int i = blockIdx.x * 256 + threadIdx.x;   // 16384
    int n = i >> 7, k = i & 127;
    Wt[n * 128 + k] = f2bf(W[k * 128 + n]);
}

// ---------------- pass 1: count + per-edge ordinal ----------------
__global__ void k_count(const int4* __restrict__ dst4, int* __restrict__ cnt,
                        int4* __restrict__ ord4) {
    int i = blockIdx.x * blockDim.x + threadIdx.x;
    if (i >= N_EDGES / 4) return;
    int4 d = dst4[i];
    int4 o;
    o.x = atomicAdd(&cnt[d.x], 1);
    o.y = atomicAdd(&cnt[d.y], 1);
    o.z = atomicAdd(&cnt[d.z], 1);
    o.w = atomicAdd(&cnt[d.w], 1);
    ord4[i] = o;
}

// ---------------- exclusive scan (3 kernels) ----------------
__global__ void k_scan1(const int* __restrict__ cnt, int* __restrict__ rowptr,
                        int* __restrict__ bsum, int n) {
    __shared__ int sh[256];
    int t = threadIdx.x;
    int i = blockIdx.x * 256 + t;
    int v = (i < n) ? cnt[i] : 0;
    sh[t] = v;
    __syncthreads();
    for (int off = 1; off < 256; off <<= 1) {
        int x = 0;
        if (t >= off) x = sh[t - off];
        __syncthreads();
        sh[t] += x;
        __syncthreads();
    }
    if (i < n) rowptr[i] = sh[t] - v;
    if (t == 255) bsum[blockIdx.x] = sh[255];
}

__global__ void k_scan2(int* __restrict__ bsum, int nb) {
    __shared__ int sh[256];
    int t = threadIdx.x;
    int v = (t < nb) ? bsum[t] : 0;
    sh[t] = v;
    __syncthreads();
    for (int off = 1; off < 256; off <<= 1) {
        int x = 0;
        if (t >= off) x = sh[t - off];
        __syncthreads();
        sh[t] += x;
        __syncthreads();
    }
    if (t < nb) bsum[t] = sh[t] - v;
}

__global__ void k_scan3(int* __restrict__ rowptr, const int* __restrict__ bsum, int n) {
    int t = threadIdx.x;
    int i = blockIdx.x * 256 + t;
    if (i < n) rowptr[i] += bsum[blockIdx.x];
    if (blockIdx.x == 0 && t == 0) rowptr[n] = N_EDGES;
}

// ---------------- pass 2: scatter into CSR (NO atomics) ----------------
__global__ void k_scatter(const int* __restrict__ src, const int* __restrict__ dst,
                          const float* __restrict__ ew, const int* __restrict__ ord,
                          const int* __restrict__ rowptr,
                          int* __restrict__ esrc, float* __restrict__ ew2) {
    int e = blockIdx.x * blockDim.x + threadIdx.x;
    if (e >= N_EDGES) return;
    int pos = rowptr[dst[e]] + ord[e];
    esrc[pos] = src[e];
    ew2[pos]  = ew[e];
}

// ---------------- per-node degree -> dinv ----------------
__global__ void k_deg(const int* __restrict__ rowptr, const float* __restrict__ ew2,
                      float* __restrict__ dinv) {
    int i = blockIdx.x * blockDim.x + threadIdx.x;
    if (i >= N_NODES) return;
    int p1 = rowptr[i + 1];
    float s = 1.0f;
    for (int p = rowptr[i]; p < p1; ++p) s += ew2[p];
    dinv[i] = rsqrtf(s);
}

// ---------------- per-node edge norms ----------------
__global__ void k_norm(const int* __restrict__ rowptr, const int* __restrict__ esrc,
                       const float* __restrict__ ew2, const float* __restrict__ dinv,
                       float* __restrict__ enorm) {
    int i = blockIdx.x * blockDim.x + threadIdx.x;
    if (i >= N_NODES) return;
    float di = dinv[i];
    int p  = rowptr[i];
    int p1 = rowptr[i + 1];
    for (; p + 4 <= p1; p += 4) {
        int s0 = esrc[p], s1 = esrc[p+1], s2 = esrc[p+2], s3 = esrc[p+3];
        float d0 = dinv[s0], d1 = dinv[s1], d2 = dinv[s2], d3 = dinv[s3];
        enorm[p]   = d0 * ew2[p]   * di;
        enorm[p+1] = d1 * ew2[p+1] * di;
        enorm[p+2] = d2 * ew2[p+2] * di;
        enorm[p+3] = d3 * ew2[p+3] * di;
    }
    for (; p < p1; ++p) enorm[p] = dinv[esrc[p]] * ew2[p] * di;
}

// ---------------- MFMA GEMM: Yb[M,128](bf16) = Xb[M,128](bf16) @ Wt^T -------
// Wt is [n][k] bf16 (pre-transposed). Tile 64 rows, full N=128, full K=128.
// LDS 48KB (A 16K + B 32K) -> 3 blocks/CU. 16B-granule XOR swizzle (q^(r&7))
// makes staging writes and fragment reads conflict-free (<=2-way).
__global__ __launch_bounds__(256) void k_gemm_mfma(const unsigned short* __restrict__ Xb,
                                                   const unsigned short* __restrict__ Wt,
                                                   unsigned short* __restrict__ Yb, int M) {
    __shared__ unsigned short Al[64 * 128];    // 16 KB
    __shared__ unsigned short Bl[128 * 128];   // 32 KB
    int t = threadIdx.x;
    int row0 = blockIdx.x * 64;

    // stage B (Wt): 128 rows x 16 granules of 8 bf16
    for (int i = t; i < 2048; i += 256) {
        int r = i >> 4, q = i & 15;
        *(bf16x8*)(Bl + r * 128 + ((q ^ (r & 7)) << 3)) =
            *(const bf16x8*)(Wt + r * 128 + (q << 3));
    }
    // stage A (Xb rows row0..row0+63): 64 rows x 16 granules
    for (int i = t; i < 1024; i += 256) {
        int r = i >> 4, q = i & 15;
        int gr = row0 + r;
        bf16x8 v;
        if (gr < M) {
            v = *(const bf16x8*)(Xb + (size_t)gr * 128 + (q << 3));
        } else {
#pragma unroll
            for (int j = 0; j < 8; ++j) v[j] = (__bf16)0.0f;
        }
        *(bf16x8*)(Al + r * 128 + ((q ^ (r & 7)) << 3)) = v;
    }
    __syncthreads();

    int l  = t & 63;
    int w  = t >> 6;                 // wave id: rows w*16..w*16+15
    int ar = (w << 4) + (l & 15);    // A lds row
    int kq = l >> 4;                 // 0..3 -> k-offset (l>>4)*8 within step

    bf16x8 af[4];
#pragma unroll
    for (int s = 0; s < 4; ++s) {
        int g = ((s << 2) + kq) ^ (l & 7);
        af[s] = *(const bf16x8*)(Al + ar * 128 + (g << 3));
    }

    f32x4 acc[8];
#pragma unroll
    for (int c = 0; c < 8; ++c)
#pragma unroll
        for (int j = 0; j < 4; ++j) acc[c][j] = 0.0f;

#pragma unroll
    for (int c = 0; c < 8; ++c) {
        int br = (c << 4) + (l & 15);    // B lds row = output col
#pragma unroll
        for (int s = 0; s < 4; ++s) {
            int g = ((s << 2) + kq) ^ (l & 7);
            bf16x8 bf = *(const bf16x8*)(Bl + br * 128 + (g << 3));
            acc[c] = __builtin_amdgcn_mfma_f32_16x16x32_bf16(af[s], bf, acc[c], 0, 0, 0);
        }
    }

    // C layout: col = lane&15, row = (lane>>4)*4 + reg  (m89-verified)
    int orow = row0 + (w << 4) + ((l >> 4) << 2);
    int ocol = l & 15;
#pragma unroll
    for (int c = 0; c < 8; ++c) {
#pragma unroll
        for (int j = 0; j < 4; ++j) {
            int r = orow + j;
            if (r < M) Yb[(size_t)r * 128 + (c << 4) + ocol] = f2bf(acc[c][j]);
        }
    }
}

// ---------------- aggregation: one wave/node, scalar edge metadata, 12-deep --
// MODE 0: out = relu(agg + bias) packed bf16 (feeds MFMA GEMM2)
// MODE 1: fused classifier: r = relu(agg + bias); out = r @ Wc + bc (fp32)
template <int MODE>
__global__ __launch_bounds__(256) void k_agg(const unsigned* __restrict__ hb,
                                             const int* __restrict__ rowptr,
                                             const int* __restrict__ esrc,
                                             const float* __restrict__ enorm,
                                             const float* __restrict__ dinv,
                                             const float* __restrict__ bias,
                                             const float* __restrict__ Wc,
                                             const float* __restrict__ bc,
                                             float* __restrict__ out) {
    int wid  = (blockIdx.x * blockDim.x + threadIdx.x) >> 6;
    int lane = threadIdx.x & 63;
    if (wid >= N_NODES) return;
    wid = __builtin_amdgcn_readfirstlane(wid);
    int p  = __builtin_amdgcn_readfirstlane(rowptr[wid]);
    int p1 = __builtin_amdgcn_readfirstlane(rowptr[wid + 1]);
    float di  = dinv[wid];
    float di2 = di * di;
    unsigned sv = hb[(size_t)wid * 64 + lane];
    float2 acc;
    acc.x = __uint_as_float(sv << 16) * di2;
    acc.y = __uint_as_float(sv & 0xffff0000u) * di2;

    while (p + 12 <= p1) {
        int s[12]; float w[12]; unsigned v[12];
#pragma unroll
        for (int i = 0; i < 12; ++i) {
            s[i] = __builtin_amdgcn_readfirstlane(esrc[p + i]);
            w[i] = enorm[p + i];
        }
#pragma unroll
        for (int i = 0; i < 12; ++i) v[i] = hb[(size_t)s[i] * 64 + lane];
#pragma unroll
        for (int i = 0; i < 12; ++i) {
            acc.x += w[i] * __uint_as_float(v[i] << 16);
            acc.y += w[i] * __uint_as_float(v[i] & 0xffff0000u);
        }
        p += 12;
    }
    while (p + 4 <= p1) {
        int s[4]; float w[4]; unsigned v[4];
#pragma unroll
        for (int i = 0; i < 4; ++i) {
            s[i] = __builtin_amdgcn_readfirstlane(esrc[p + i]);
            w[i] = enorm[p + i];
        }
#pragma unroll
        for (int i = 0; i < 4; ++i) v[i] = hb[(size_t)s[i] * 64 + lane];
#pragma unroll
        for (int i = 0; i < 4; ++i) {
            acc.x += w[i] * __uint_as_float(v[i] << 16);
            acc.y += w[i] * __uint_as_float(v[i] & 0xffff0000u);
        }
        p += 4;
    }
    for (; p < p1; ++p) {
        int s = __builtin_amdgcn_readfirstlane(esrc[p]);
        float w = enorm[p];
        unsigned v = hb[(size_t)s * 64 + lane];
        acc.x += w * __uint_as_float(v << 16);
        acc.y += w * __uint_as_float(v & 0xffff0000u);
    }

    float2 bv = ((const float2*)bias)[lane];
    acc.x = fmaxf(acc.x + bv.x, 0.f);
    acc.y = fmaxf(acc.y + bv.y, 0.f);
    if (MODE == 0) {
        unsigned lo = f2bf(acc.x), hi = f2bf(acc.y);
        ((unsigned*)out)[(size_t)wid * 64 + lane] = lo | (hi << 16);
    } else {
        int k0 = 2 * lane;
        float r[NC];
#pragma unroll
        for (int c = 0; c < NC; ++c)
            r[c] = acc.x * Wc[k0 * NC + c] + acc.y * Wc[(k0 + 1) * NC + c];
#pragma unroll
        for (int off = 32; off; off >>= 1)
#pragma unroll
            for (int c = 0; c < NC; ++c)
                r[c] += __shfl_xor(r[c], off, 64);
        if (lane < NC) out[(size_t)wid * NC + lane] = r[lane] + bc[lane];
    }
}

extern "C" void kernel_launch(void* const* d_in, const int* in_sizes, int n_in,
                              void* d_out, int out_size, void* d_ws, size_t ws_size,
                              hipStream_t stream) {
    const float* x   = (const float*)d_in[0];
    const int*   ei  = (const int*)d_in[1];
    const float* ew  = (const float*)d_in[2];
    const float* W1  = (const float*)d_in[3];
    const float* b1  = (const float*)d_in[4];
    const float* W2  = (const float*)d_in[5];
    const float* b2  = (const float*)d_in[6];
    const float* Wc  = (const float*)d_in[7];
    const float* bc  = (const float*)d_in[8];
    float*       out = (float*)d_out;

    const int* src = ei;
    const int* dst = ei + N_EDGES;

    size_t off = 0;
    auto carve = [&](size_t bytes) {
        void* p = (char*)d_ws + off;
        off += (bytes + 255) & ~(size_t)255;
        return p;
    };
    unsigned short* xb  = (unsigned short*)carve((size_t)N_NODES * 128 * 2);
    unsigned short* hb  = (unsigned short*)carve((size_t)N_NODES * 128 * 2);
    unsigned short* hb1 = (unsigned short*)carve((size_t)N_NODES * 128 * 2);
    unsigned short* wt1 = (unsigned short*)carve(128 * 128 * 2);
    unsigned short* wt2 = (unsigned short*)carve(128 * 128 * 2);
    float* dinv   = (float*)carve((size_t)N_NODES * 4);
    int*   cnt    = (int*)carve((size_t)N_NODES * 4);
    int*   rowptr = (int*)carve((size_t)(N_NODES + 1) * 4);
    int*   bsum   = (int*)carve(256 * 4);
    int*   ord    = (int*)carve((size_t)N_EDGES * 4);
    int*   esrc   = (int*)carve((size_t)N_EDGES * 4);
    float* ew2    = (float*)carve((size_t)N_EDGES * 4);
    float* enorm  = (float*)carve((size_t)N_EDGES * 4);
    (void)ws_size; (void)n_in; (void)in_sizes; (void)out_size;

    int eb = (N_EDGES + 255) / 256;
    int nb = (N_NODES + 255) / 256;

    // CSR build
    k_zero<<<(N_NODES / 4 + 255) / 256, 256, 0, stream>>>((int4*)cnt, N_NODES / 4);
    k_count<<<(N_EDGES / 4 + 255) / 256, 256, 0, stream>>>((const int4*)dst, cnt, (int4*)ord);
    k_scan1<<<nb, 256, 0, stream>>>(cnt, rowptr, bsum, N_NODES);
    k_scan2<<<1, 256, 0, stream>>>(bsum, nb);
    k_scan3<<<nb, 256, 0, stream>>>(rowptr, bsum, N_NODES);
    k_scatter<<<eb, 256, 0, stream>>>(src, dst, ew, ord, rowptr, esrc, ew2);
    k_deg<<<nb, 256, 0, stream>>>(rowptr, ew2, dinv);
    k_norm<<<nb, 256, 0, stream>>>(rowptr, esrc, ew2, dinv, enorm);

    // precision prep
    int n4 = N_NODES * 128 / 4;
    k_x2b<<<(n4 + 255) / 256, 256, 0, stream>>>((const float4*)x, (ushort4*)xb, n4);
    k_wt<<<64, 256, 0, stream>>>(W1, wt1);
    k_wt<<<64, 256, 0, stream>>>(W2, wt2);

    int gb = (N_NODES + 63) / 64;
    // layer 1
    k_gemm_mfma<<<gb, 256, 0, stream>>>(xb, wt1, hb, N_NODES);
    k_agg<0><<<(N_NODES + 3) / 4, 256, 0, stream>>>((const unsigned*)hb, rowptr, esrc,
                                                    enorm, dinv, b1, Wc, bc, (float*)hb1);
    // layer 2 + fused classifier
    k_gemm_mfma<<<gb, 256, 0, stream>>>(hb1, wt2, hb, N_NODES);
    k_agg<1><<<(N_NODES + 3) / 4, 256, 0, stream>>>((const unsigned*)hb, rowptr, esrc,
                                                    enorm, dinv, b2, Wc, bc, out);
}

// Round 8
// 157.933 us; speedup vs baseline: 2.2451x; 1.0917x over previous
//
#include <hip/hip_runtime.h>
#include <hip/hip_bf16.h>

#define N_NODES 50000
#define N_EDGES 600000
#define NC 10
#define GB ((N_NODES + 63) / 64)

typedef __attribute__((ext_vector_type(8))) __bf16 bf16x8;
typedef __attribute__((ext_vector_type(8))) unsigned short u16x8;
typedef __attribute__((ext_vector_type(4))) float f32x4;

__device__ __forceinline__ unsigned short f2bf(float f) {
    unsigned u = __float_as_uint(f);
    u += 0x7fff + ((u >> 16) & 1);           // round-to-nearest-even
    return (unsigned short)(u >> 16);
}
__device__ __forceinline__ int rfl(int x) { return __builtin_amdgcn_readfirstlane(x); }
__device__ __forceinline__ float rflf(float x) {
    return __uint_as_float(__builtin_amdgcn_readfirstlane(__float_as_uint(x)));
}

// ---------------- zero helper ----------------
__global__ void k_zero(int4* __restrict__ p, int n4) {
    int i = blockIdx.x * blockDim.x + threadIdx.x;
    if (i < n4) p[i] = make_int4(0, 0, 0, 0);
}

// ---------------- prep: W transposes + edge count (fused, independent) ------
__global__ void k_prep(const float* __restrict__ W1, const float* __restrict__ W2,
                       unsigned short* __restrict__ wt1, unsigned short* __restrict__ wt2,
                       const int4* __restrict__ dst4, int* __restrict__ cnt,
                       int4* __restrict__ ord4) {
    int b = blockIdx.x;
    if (b < 128) {
        const float* W = (b < 64) ? W1 : W2;
        unsigned short* Wt = (b < 64) ? wt1 : wt2;
        int i = (b & 63) * 256 + threadIdx.x;    // 0..16383
        int n = i >> 7, k = i & 127;
        Wt[n * 128 + k] = f2bf(W[k * 128 + n]);
    } else {
        int i = (b - 128) * 256 + threadIdx.x;
        if (i < N_EDGES / 4) {
            int4 d = dst4[i];
            int4 o;
            o.x = atomicAdd(&cnt[d.x], 1);
            o.y = atomicAdd(&cnt[d.y], 1);
            o.z = atomicAdd(&cnt[d.z], 1);
            o.w = atomicAdd(&cnt[d.w], 1);
            ord4[i] = o;
        }
    }
}

// ---------------- exclusive scan (3 kernels) ----------------
__global__ void k_scan1(const int* __restrict__ cnt, int* __restrict__ rowptr,
                        int* __restrict__ bsum, int n) {
    __shared__ int sh[256];
    int t = threadIdx.x;
    int i = blockIdx.x * 256 + t;
    int v = (i < n) ? cnt[i] : 0;
    sh[t] = v;
    __syncthreads();
    for (int off = 1; off < 256; off <<= 1) {
        int x = 0;
        if (t >= off) x = sh[t - off];
        __syncthreads();
        sh[t] += x;
        __syncthreads();
    }
    if (i < n) rowptr[i] = sh[t] - v;
    if (t == 255) bsum[blockIdx.x] = sh[255];
}

__global__ void k_scan2(int* __restrict__ bsum, int nb) {
    __shared__ int sh[256];
    int t = threadIdx.x;
    int v = (t < nb) ? bsum[t] : 0;
    sh[t] = v;
    __syncthreads();
    for (int off = 1; off < 256; off <<= 1) {
        int x = 0;
        if (t >= off) x = sh[t - off];
        __syncthreads();
        sh[t] += x;
        __syncthreads();
    }
    if (t < nb) bsum[t] = sh[t] - v;
}

__global__ void k_scan3(int* __restrict__ rowptr, const int* __restrict__ bsum, int n) {
    int t = threadIdx.x;
    int i = blockIdx.x * 256 + t;
    if (i < n) rowptr[i] += bsum[blockIdx.x];
    if (blockIdx.x == 0 && t == 0) rowptr[n] = N_EDGES;
}

// ---------------- shared GEMM body (MFMA, bf16) ----------------
// Tile 64 rows x full N=128 x full K=128. 16B-granule XOR swizzle (q^(r&7)).
template <int FP32IN>
__device__ __forceinline__ void gemm_body(unsigned short* Al, unsigned short* Bl,
                                          const void* __restrict__ Xin,
                                          const unsigned short* __restrict__ Wt,
                                          unsigned short* __restrict__ Yb,
                                          int M, int row0) {
    int t = threadIdx.x;
    // stage B (Wt): 128 rows x 16 granules of 8 bf16
    for (int i = t; i < 2048; i += 256) {
        int r = i >> 4, q = i & 15;
        *(u16x8*)(Bl + r * 128 + ((q ^ (r & 7)) << 3)) =
            *(const u16x8*)(Wt + r * 128 + (q << 3));
    }
    // stage A: 64 rows x 16 granules (convert fp32->bf16 in-flight if needed)
    for (int i = t; i < 1024; i += 256) {
        int r = i >> 4, q = i & 15;
        int gr = row0 + r;
        u16x8 v;
        if (FP32IN) {
            const float* X = (const float*)Xin;
            if (gr < M) {
                float4 f0 = *(const float4*)(X + (size_t)gr * 128 + (q << 3));
                float4 f1 = *(const float4*)(X + (size_t)gr * 128 + (q << 3) + 4);
                v[0] = f2bf(f0.x); v[1] = f2bf(f0.y); v[2] = f2bf(f0.z); v[3] = f2bf(f0.w);
                v[4] = f2bf(f1.x); v[5] = f2bf(f1.y); v[6] = f2bf(f1.z); v[7] = f2bf(f1.w);
            } else {
#pragma unroll
                for (int j = 0; j < 8; ++j) v[j] = 0;
            }
        } else {
            const unsigned short* X = (const unsigned short*)Xin;
            if (gr < M) {
                v = *(const u16x8*)(X + (size_t)gr * 128 + (q << 3));
            } else {
#pragma unroll
                for (int j = 0; j < 8; ++j) v[j] = 0;
            }
        }
        *(u16x8*)(Al + r * 128 + ((q ^ (r & 7)) << 3)) = v;
    }
    __syncthreads();

    int l  = t & 63;
    int w  = t >> 6;                 // wave id: rows w*16..w*16+15
    int ar = (w << 4) + (l & 15);
    int kq = l >> 4;

    bf16x8 af[4];
#pragma unroll
    for (int s = 0; s < 4; ++s) {
        int g = ((s << 2) + kq) ^ (l & 7);
        af[s] = *(const bf16x8*)(Al + ar * 128 + (g << 3));
    }

    f32x4 acc[8];
#pragma unroll
    for (int c = 0; c < 8; ++c)
#pragma unroll
        for (int j = 0; j < 4; ++j) acc[c][j] = 0.0f;

#pragma unroll
    for (int c = 0; c < 8; ++c) {
        int br = (c << 4) + (l & 15);
#pragma unroll
        for (int s = 0; s < 4; ++s) {
            int g = ((s << 2) + kq) ^ (l & 7);
            bf16x8 bf = *(const bf16x8*)(Bl + br * 128 + (g << 3));
            acc[c] = __builtin_amdgcn_mfma_f32_16x16x32_bf16(af[s], bf, acc[c], 0, 0, 0);
        }
    }

    int orow = row0 + (w << 4) + ((l >> 4) << 2);
    int ocol = l & 15;
#pragma unroll
    for (int c = 0; c < 8; ++c) {
#pragma unroll
        for (int j = 0; j < 4; ++j) {
            int r = orow + j;
            if (r < M) Yb[(size_t)r * 128 + (c << 4) + ocol] = f2bf(acc[c][j]);
        }
    }
}

// ---------------- fused: GEMM1 (fp32 x) + CSR scatter (independent) ---------
__global__ __launch_bounds__(256) void k_sg(const float* __restrict__ X,
                                            const unsigned short* __restrict__ Wt,
                                            unsigned short* __restrict__ Yb, int M,
                                            const int* __restrict__ src,
                                            const int* __restrict__ dst,
                                            const float* __restrict__ ew,
                                            const int* __restrict__ ord,
                                            const int* __restrict__ rowptr,
                                            int* __restrict__ esrc,
                                            float* __restrict__ ew2) {
    __shared__ unsigned short Al[64 * 128];
    __shared__ unsigned short Bl[128 * 128];
    if (blockIdx.x < GB) {
        gemm_body<1>(Al, Bl, X, Wt, Yb, M, blockIdx.x * 64);
    } else {
        int e = (blockIdx.x - GB) * 256 + threadIdx.x;
        if (e < N_EDGES) {
            int pos = rowptr[dst[e]] + ord[e];
            esrc[pos] = src[e];
            ew2[pos]  = ew[e];
        }
    }
}

// ---------------- standalone GEMM (bf16 in, layer 2) ----------------
__global__ __launch_bounds__(256) void k_gemm_mfma(const unsigned short* __restrict__ Xb,
                                                   const unsigned short* __restrict__ Wt,
                                                   unsigned short* __restrict__ Yb, int M) {
    __shared__ unsigned short Al[64 * 128];
    __shared__ unsigned short Bl[128 * 128];
    gemm_body<0>(Al, Bl, Xb, Wt, Yb, M, blockIdx.x * 64);
}

// ---------------- per-node degree -> dinv ----------------
__global__ void k_deg(const int* __restrict__ rowptr, const float* __restrict__ ew2,
                      float* __restrict__ dinv) {
    int i = blockIdx.x * blockDim.x + threadIdx.x;
    if (i >= N_NODES) return;
    int p1 = rowptr[i + 1];
    float s = 1.0f;
    for (int p = rowptr[i]; p < p1; ++p) s += ew2[p];
    dinv[i] = rsqrtf(s);
}

// ---------------- per-node edge norms ----------------
__global__ void k_norm(const int* __restrict__ rowptr, const int* __restrict__ esrc,
                       const float* __restrict__ ew2, const float* __restrict__ dinv,
                       float* __restrict__ enorm) {
    int i = blockIdx.x * blockDim.x + threadIdx.x;
    if (i >= N_NODES) return;
    float di = dinv[i];
    int p  = rowptr[i];
    int p1 = rowptr[i + 1];
    for (; p + 4 <= p1; p += 4) {
        int s0 = esrc[p], s1 = esrc[p+1], s2 = esrc[p+2], s3 = esrc[p+3];
        float d0 = dinv[s0], d1 = dinv[s1], d2 = dinv[s2], d3 = dinv[s3];
        enorm[p]   = d0 * ew2[p]   * di;
        enorm[p+1] = d1 * ew2[p+1] * di;
        enorm[p+2] = d2 * ew2[p+2] * di;
        enorm[p+3] = d3 * ew2[p+3] * di;
    }
    for (; p < p1; ++p) enorm[p] = dinv[esrc[p]] * ew2[p] * di;
}

// ---------------- aggregation: one wave/node, all-scalar metadata, 16-deep --
// MODE 0: out = relu(agg + bias) packed bf16 (feeds MFMA GEMM2)
// MODE 1: fused classifier: r = relu(agg + bias); out = r @ Wc + bc (fp32)
template <int MODE>
__global__ __launch_bounds__(256) void k_agg(const unsigned* __restrict__ hb,
                                             const int* __restrict__ rowptr,
                                             const int* __restrict__ esrc,
                                             const float* __restrict__ enorm,
                                             const float* __restrict__ dinv,
                                             const float* __restrict__ bias,
                                             const float* __restrict__ Wc,
                                             const float* __restrict__ bc,
                                             float* __restrict__ out) {
    int wid  = (blockIdx.x * blockDim.x + threadIdx.x) >> 6;
    int lane = threadIdx.x & 63;
    if (wid >= N_NODES) return;
    wid = rfl(wid);
    int p  = rfl(rowptr[wid]);
    int p1 = rfl(rowptr[wid + 1]);
    float di  = dinv[wid];
    float di2 = di * di;
    unsigned sv = hb[(size_t)wid * 64 + lane];
    float2 acc;
    acc.x = __uint_as_float(sv << 16) * di2;
    acc.y = __uint_as_float(sv & 0xffff0000u) * di2;

    // 16-deep gather pipeline; esrc AND enorm via scalar (SMEM) path so the
    // vector-memory queue holds only h-row gathers.
    while (p + 16 <= p1) {
        int s[16]; float w[16]; unsigned v[16];
#pragma unroll
        for (int i = 0; i < 16; ++i) {
            s[i] = rfl(esrc[p + i]);
            w[i] = rflf(enorm[p + i]);
        }
#pragma unroll
        for (int i = 0; i < 16; ++i) v[i] = hb[(size_t)s[i] * 64 + lane];
#pragma unroll
        for (int i = 0; i < 16; ++i) {
            acc.x += w[i] * __uint_as_float(v[i] << 16);
            acc.y += w[i] * __uint_as_float(v[i] & 0xffff0000u);
        }
        p += 16;
    }
    while (p + 4 <= p1) {
        int s[4]; float w[4]; unsigned v[4];
#pragma unroll
        for (int i = 0; i < 4; ++i) {
            s[i] = rfl(esrc[p + i]);
            w[i] = rflf(enorm[p + i]);
        }
#pragma unroll
        for (int i = 0; i < 4; ++i) v[i] = hb[(size_t)s[i] * 64 + lane];
#pragma unroll
        for (int i = 0; i < 4; ++i) {
            acc.x += w[i] * __uint_as_float(v[i] << 16);
            acc.y += w[i] * __uint_as_float(v[i] & 0xffff0000u);
        }
        p += 4;
    }
    for (; p < p1; ++p) {
        int s = rfl(esrc[p]);
        float w = rflf(enorm[p]);
        unsigned v = hb[(size_t)s * 64 + lane];
        acc.x += w * __uint_as_float(v << 16);
        acc.y += w * __uint_as_float(v & 0xffff0000u);
    }

    float2 bv = ((const float2*)bias)[lane];
    acc.x = fmaxf(acc.x + bv.x, 0.f);
    acc.y = fmaxf(acc.y + bv.y, 0.f);
    if (MODE == 0) {
        unsigned lo = f2bf(acc.x), hi = f2bf(acc.y);
        ((unsigned*)out)[(size_t)wid * 64 + lane] = lo | (hi << 16);
    } else {
        int k0 = 2 * lane;
        float r[NC];
#pragma unroll
        for (int c = 0; c < NC; ++c)
            r[c] = acc.x * Wc[k0 * NC + c] + acc.y * Wc[(k0 + 1) * NC + c];
#pragma unroll
        for (int off = 32; off; off >>= 1)
#pragma unroll
            for (int c = 0; c < NC; ++c)
                r[c] += __shfl_xor(r[c], off, 64);
        if (lane < NC) out[(size_t)wid * NC + lane] = r[lane] + bc[lane];
    }
}

extern "C" void kernel_launch(void* const* d_in, const int* in_sizes, int n_in,
                              void* d_out, int out_size, void* d_ws, size_t ws_size,
                              hipStream_t stream) {
    const float* x   = (const float*)d_in[0];
    const int*   ei  = (const int*)d_in[1];
    const float* ew  = (const float*)d_in[2];
    const float* W1  = (const float*)d_in[3];
    const float* b1  = (const float*)d_in[4];
    const float* W2  = (const float*)d_in[5];
    const float* b2  = (const float*)d_in[6];
    const float* Wc  = (const float*)d_in[7];
    const float* bc  = (const float*)d_in[8];
    float*       out = (float*)d_out;

    const int* src = ei;
    const int* dst = ei + N_EDGES;

    size_t off = 0;
    auto carve = [&](size_t bytes) {
        void* p = (char*)d_ws + off;
        off += (bytes + 255) & ~(size_t)255;
        return p;
    };
    unsigned short* hb  = (unsigned short*)carve((size_t)N_NODES * 128 * 2);
    unsigned short* hb1 = (unsigned short*)carve((size_t)N_NODES * 128 * 2);
    unsigned short* wt1 = (unsigned short*)carve(128 * 128 * 2);
    unsigned short* wt2 = (unsigned short*)carve(128 * 128 * 2);
    float* dinv   = (float*)carve((size_t)N_NODES * 4);
    int*   cnt    = (int*)carve((size_t)N_NODES * 4);
    int*   rowptr = (int*)carve((size_t)(N_NODES + 1) * 4);
    int*   bsum   = (int*)carve(256 * 4);
    int*   ord    = (int*)carve((size_t)N_EDGES * 4);
    int*   esrc   = (int*)carve((size_t)N_EDGES * 4);
    float* ew2    = (float*)carve((size_t)N_EDGES * 4);
    float* enorm  = (float*)carve((size_t)N_EDGES * 4);
    (void)ws_size; (void)n_in; (void)in_sizes; (void)out_size;

    int nb = (N_NODES + 255) / 256;
    int eb = (N_EDGES + 255) / 256;

    // CSR build + weight prep (fused where independent)
    k_zero<<<(N_NODES / 4 + 255) / 256, 256, 0, stream>>>((int4*)cnt, N_NODES / 4);
    k_prep<<<128 + (N_EDGES / 4 + 255) / 256, 256, 0, stream>>>(
        W1, W2, wt1, wt2, (const int4*)dst, cnt, (int4*)ord);
    k_scan1<<<nb, 256, 0, stream>>>(cnt, rowptr, bsum, N_NODES);
    k_scan2<<<1, 256, 0, stream>>>(bsum, nb);
    k_scan3<<<nb, 256, 0, stream>>>(rowptr, bsum, N_NODES);
    // GEMM1 (x fp32 -> hb bf16) fused with CSR scatter (independent work)
    k_sg<<<GB + eb, 256, 0, stream>>>(x, wt1, hb, N_NODES,
                                      src, dst, ew, ord, rowptr, esrc, ew2);
    k_deg<<<nb, 256, 0, stream>>>(rowptr, ew2, dinv);
    k_norm<<<nb, 256, 0, stream>>>(rowptr, esrc, ew2, dinv, enorm);

    // layer 1 aggregation -> bf16
    k_agg<0><<<(N_NODES + 3) / 4, 256, 0, stream>>>((const unsigned*)hb, rowptr, esrc,
                                                    enorm, dinv, b1, Wc, bc, (float*)hb1);
    // layer 2 GEMM + aggregation + fused classifier
    k_gemm_mfma<<<GB, 256, 0, stream>>>(hb1, wt2, hb, N_NODES);
    k_agg<1><<<(N_NODES + 3) / 4, 256, 0, stream>>>((const unsigned*)hb, rowptr, esrc,
                                                    enorm, dinv, b2, Wc, bc, out);
}